// Round 14
// baseline (875.280 us; speedup 1.0000x reference)
//
#include <hip/hip_runtime.h>
#include <cstdint>

#define DEV static __device__ __forceinline__

typedef __attribute__((ext_vector_type(8))) short short8v;     // 8 x bf16 bits
typedef __attribute__((ext_vector_type(4))) float f32x4;
typedef __attribute__((ext_vector_type(4))) float fl4;
typedef __attribute__((ext_vector_type(4))) unsigned short us4;
typedef __attribute__((ext_vector_type(8))) unsigned short us8;

DEV float b2f(unsigned short u) {
  union { unsigned int i; float f; } c; c.i = ((unsigned int)u) << 16; return c.f;
}
DEV unsigned short f2b(float f) {   // RNE float -> bf16 bits
  union { float f; unsigned int i; } c; c.f = f;
  unsigned int u = c.i;
  u += 0x7fffu + ((u >> 16) & 1u);
  return (unsigned short)(u >> 16);
}

DEV void gload16(const void* g, void* l) {  // async global->LDS, 16B/lane
  __builtin_amdgcn_global_load_lds(
      (const __attribute__((address_space(1))) unsigned int*)g,
      (__attribute__((address_space(3))) unsigned int*)l, 16, 0, 0);
}

DEV float red16(float v) {  // reduce across 16 lanes sharing lk (xor low 4 bits)
  v += __shfl_xor(v, 1); v += __shfl_xor(v, 2);
  v += __shfl_xor(v, 4); v += __shfl_xor(v, 8);
  return v;
}
DEV float red4lk(float v) { // reduce across the 4 lk groups (xor bits 4,5)
  v += __shfl_xor(v, 16); v += __shfl_xor(v, 32);
  return v;
}

// ---------------- elementwise f32 -> bf16 ----------------
__global__ __launch_bounds__(256) void k_f32_to_bf16(const float* __restrict__ src,
                                                     unsigned short* __restrict__ dst, long n) {
  long i = ((long)blockIdx.x * 256 + threadIdx.x) * 4;
  if (i >= n) return;
  fl4 v = *(const fl4*)(src + i);
  us4 o;
  o[0] = f2b(v[0]); o[1] = f2b(v[1]); o[2] = f2b(v[2]); o[3] = f2b(v[3]);
  *(us4*)(dst + i) = o;
}

// ---------------- concat biases into 3072-float buffer ----------------
__global__ __launch_bounds__(256) void k_bias_cat(const float* __restrict__ bq,
                                                  const float* __restrict__ bk,
                                                  const float* __restrict__ bv,
                                                  float* __restrict__ o) {
  const int t = blockIdx.x * 256 + threadIdx.x;   // 3072
  o[t] = t < 1024 ? bq[t] : (t < 2048 ? bk[t - 1024] : bv[t - 2048]);
}

// ---------------- finalize inverse norms ----------------
__global__ __launch_bounds__(256) void k_norms_fin(const float* __restrict__ pq,
                                                   const float* __restrict__ pk,
                                                   float* __restrict__ invq, float* __restrict__ invk) {
  const int gid = blockIdx.x * 256 + threadIdx.x;   // 16384
  invq[gid] = rsqrtf(pq[gid]);
  invk[gid] = rsqrtf(pk[gid]);
}

// ---------------- finalize tailor: 1/(L + rowsum(S) + eps*invq*colsum(Q)) ----------------
__global__ __launch_bounds__(256) void k_tailor_fin(const float* __restrict__ Srow,
                                                    const float* __restrict__ invq,
                                                    const float* __restrict__ qsum,
                                                    float* __restrict__ tailor) {
  const int gid = blockIdx.x * 256 + threadIdx.x;   // 16384
  tailor[gid] = 1.0f / (1024.0f + Srow[gid] + 1e-6f * invq[gid] * qsum[gid]);
}

#define MFMA_BF16 __builtin_amdgcn_mfma_f32_16x16x32_bf16
#define SBAR   __builtin_amdgcn_s_barrier()

// ---------------- 256x256 NT GEMM, BK=32, 16 waves (4Mx4N), A-in-LDS / B-direct -------
// LDS-BANDWIDTH round: B operand is NOT staged in LDS — each wave loads its B fragments
// directly from global into registers, one tile ahead (static Bc/Bn ping-pong, 2x-unrolled
// loop). The 4 waves sharing wcn read IDENTICAL B addresses -> B-tile (16 KB) is L1-hot,
// 3 of 4 waves hit L1. LDS traffic per K-tile halves: A-only 64 KB read + 16 KB write.
// A: 4 LDS K-tile buffers (64 KiB), stage t+2 at t (1 gload16 = full 16 KB with 1024 thr).
// Top-of-tile s_waitcnt vmcnt(1): issue order at tile t is [Bn(t+1) x4, stage(t+2)] so
// the NEWEST outstanding op is the A-stage; vmcnt(1) drains current A-stage + B-prefetch,
// leaves the next A-stage in flight (counted, never 0 until tail). Barrier per tile.
// LDS chunk-swizzle (verified 0-conflict) + XCD-bijective block swizzle carried over.
// Epilogues: LDS-roundtrip (verified R11-R13), 128 KiB scratch reuses LDSU.
// EPI 1: final fused fp32 epilogue.  EPI 4: scaled-S + row sums.  EPI 5: merged QKV.
template<int EPI>
__global__ __launch_bounds__(1024, 4)
void k_g256(const unsigned short* __restrict__ A,
            const unsigned short* __restrict__ Bt,
            void* __restrict__ O0, void* __restrict__ O1, void* __restrict__ O2,
            int K, long sA, long sB, long sC,
            const float* __restrict__ bias,
            float* __restrict__ r1, float* __restrict__ r2,
            float* __restrict__ r3, float* __restrict__ r4,
            const unsigned short* __restrict__ xh,
            const float* __restrict__ Vsum,
            const float* __restrict__ tailor,
            const float* __restrict__ gptr) {
  __shared__ __align__(16) unsigned short LDSU[65536];   // 128 KiB: A bufs (64K), then scratch

  const int tid = threadIdx.x;
  const int wv = tid >> 6, lane = tid & 63;
  const int wr = wv >> 2, wcn = wv & 3;          // 4 x 4 wave grid, 64x64 each
  const int l15 = lane & 15, lk = lane >> 4;

  // XCD-bijective swizzle over (x,y); nwg % 8 == 0 for all grids used
  const int nx = gridDim.x;
  const int nwg = nx * gridDim.y;
  const int lin = blockIdx.y * nx + blockIdx.x;
  const int cpx = nwg >> 3;
  const int wg = (lin & 7) * cpx + (lin >> 3);
  const int bn = wg % nx;
  const int bm = wg / nx;
  const int bz = blockIdx.z;

  const unsigned short* Ab = A + (long)bz * sA + (long)bm * 256 * K;
  const unsigned short* Bb = Bt + (long)bz * sB + (long)bn * 256 * K;

  // A staging (BK=32): 1024 threads cover a full 256x32 buffer: row = tid>>2,
  // physical chunk tid&3, pre-swizzled global chunk = (tid&3) ^ ((row>>1)&3).
  const int scsw = (tid & 3) ^ ((tid >> 3) & 3);
  const long gOff = (long)(tid >> 2) * K + (long)scsw * 8;   // + t*32
  const int ldsb = wv * 512;

  // A read-side swizzle: chunk' = lk ^ ((row>>1)&3); row bits 1-2 come from l15 only.
  const int rdsw = (lk ^ ((l15 >> 1) & 3)) * 8;
  const int abase = (wr * 64 + l15) * 32;    // + i*512

  // B direct-global fragment base: row = wcn*64 + j*16 + l15, cols lk*8..+8 of k-tile
  const long bgOff = (long)(wcn * 64 + l15) * K + (long)lk * 8;

  f32x4 acc[4][4];
#pragma unroll
  for (int i = 0; i < 4; ++i)
#pragma unroll
    for (int j = 0; j < 4; ++j) acc[i][j] = (f32x4){0.f, 0.f, 0.f, 0.f};

#define STAGEA(T, BUF) gload16(Ab + (long)(T) * 32 + gOff, LDSU + (BUF) * 8192 + ldsb);

  short8v Bc[4], Bn[4];
  // prologue: B tile 0 into Bc, then A tiles 0,1 (stage newest = tile 1)
#pragma unroll
  for (int j = 0; j < 4; ++j)
    Bc[j] = *(const short8v*)(Bb + bgOff + (long)j * 16 * K);
  STAGEA(0, 0)
  STAGEA(1, 1)

  const int NT = K >> 5;

#define GBODY(T, BCUR, BNXT)                                                      \
  {                                                                               \
    if ((T) + 1 < NT) { asm volatile("s_waitcnt vmcnt(1)" ::: "memory"); }        \
    else              { asm volatile("s_waitcnt vmcnt(0)" ::: "memory"); }        \
    SBAR;                                                                         \
    if ((T) + 1 < NT) {                                                           \
      const long kt2 = (long)((T) + 1) * 32;                                      \
      _Pragma("unroll")                                                           \
      for (int j = 0; j < 4; ++j)                                                 \
        BNXT[j] = *(const short8v*)(Bb + bgOff + (long)j * 16 * K + kt2);         \
    }                                                                             \
    if ((T) + 2 < NT) STAGEA((T) + 2, ((T) + 2) & 3)                              \
    const unsigned short* Asc = LDSU + ((T) & 3) * 8192;                          \
    short8v Af[4];                                                                \
    _Pragma("unroll")                                                             \
    for (int i = 0; i < 4; ++i)                                                   \
      Af[i] = *(const short8v*)&Asc[abase + i * 512 + rdsw];                      \
    __builtin_amdgcn_s_setprio(1);                                                \
    _Pragma("unroll")                                                             \
    for (int i = 0; i < 4; ++i)                                                   \
      _Pragma("unroll")                                                           \
      for (int j = 0; j < 4; ++j)                                                 \
        acc[i][j] = MFMA_BF16(Af[i], BCUR[j], acc[i][j], 0, 0, 0);                \
    __builtin_amdgcn_s_setprio(0);                                                \
  }

  for (int t = 0; t < NT; t += 2) {
    GBODY(t,     Bc, Bn)
    GBODY(t + 1, Bn, Bc)
  }
#undef GBODY
#undef STAGEA
  SBAR;   // all waves done with K-loop LDS -> safe to reuse as epilogue scratch

  const int row0 = bm * 256 + wr * 64;
  const int col0 = bn * 256 + wcn * 64;
  unsigned short* sc = LDSU;       // [256 rows][256 cols] bf16, cell-swizzled
  float* scf = (float*)LDSU;       // [128 rows][256 cols] fp32, cell-swizzled

  if constexpr (EPI == 1) {
    float* Cb = (float*)O0 + (long)bz * sC;
    const float g = gptr[0];
#pragma unroll
    for (int h = 0; h < 2; ++h) {
      if ((wr >> 1) == h) {
#pragma unroll
        for (int i = 0; i < 4; ++i)
#pragma unroll
          for (int j = 0; j < 4; ++j) {
            const int col = wcn * 64 + j * 16 + l15;
            const int cc = col >> 2, c3 = col & 3;
#pragma unroll
            for (int r = 0; r < 4; ++r) {
              const int rl = (wr & 1) * 64 + i * 16 + lk * 4 + r;   // [0,128)
              scf[rl * 256 + ((cc ^ (rl & 15)) << 2) + c3] = acc[i][j][r];
            }
          }
      }
      SBAR;
#pragma unroll
      for (int it = 0; it < 8; ++it) {
        const int rl = it * 16 + wv;                   // [0,128)
        const int rg = bm * 256 + h * 128 + rl;        // [0,2048)
        const int c = lane;                            // f32 cell [0,64)
        fl4 a4 = *(const fl4*)&scf[rl * 256 + ((c ^ (rl & 15)) << 2)];
        const int cg = bn * 256 + c * 4;
        us4 xv = *(const us4*)&xh[((long)bz * 2048 + rg) * 1024 + cg];
        fl4 tl = *(const fl4*)&tailor[bz * 1024 + cg];
        const float vs = Vsum[bz * 2048 + rg];
        fl4 o;
#pragma unroll
        for (int q = 0; q < 4; ++q) o[q] = b2f(xv[q]) + g * ((vs + a4[q]) * tl[q]);
        *(fl4*)&Cb[(long)rg * 1024 + cg] = o;
      }
      if (h == 0) SBAR;
    }
  } else if constexpr (EPI == 4) {
    // S[p][l] = invq[p]*invk[l]*acc; Srow[p] += scaled row sum; roundtrip -> us8 stores
    unsigned short* Cb = (unsigned short*)O0 + (long)bz * sC;
    float ivk[4];
#pragma unroll
    for (int j = 0; j < 4; ++j) ivk[j] = r3[bz * 1024 + col0 + j * 16 + l15];
#pragma unroll
    for (int i = 0; i < 4; ++i) {
      float ivq[4];
#pragma unroll
      for (int r = 0; r < 4; ++r) ivq[r] = r2[bz * 1024 + row0 + i * 16 + lk * 4 + r];
#pragma unroll
      for (int r = 0; r < 4; ++r) {
        const int rl = wr * 64 + i * 16 + lk * 4 + r;   // [0,256)
        float sm = 0.f;
#pragma unroll
        for (int j = 0; j < 4; ++j) {
          const float v = acc[i][j][r] * ivq[r] * ivk[j];
          sm += v;
          const int col = wcn * 64 + j * 16 + l15;
          sc[rl * 256 + (((col >> 3) ^ (rl & 15)) << 3) + (col & 7)] = f2b(v);
        }
        sm = red16(sm);
        if (l15 == 0) atomicAdd(&r1[(long)bz * 1024 + row0 + i * 16 + lk * 4 + r], sm);
      }
    }
    SBAR;
#pragma unroll
    for (int it = 0; it < 8; ++it) {
      const int rl = it * 32 + (tid >> 5);              // [0,256)
      const int c = lane & 31;
      us8 v = *(const us8*)&sc[rl * 256 + ((c ^ (rl & 15)) << 3)];
      *(us8*)&Cb[(long)(bm * 256 + rl) * 1024 + bn * 256 + c * 8] = v;
    }
  } else {  // EPI == 5: merged QKV
    const int seg = bn >> 2;             // 0=Q, 1=K, 2=V
    const int b = bm >> 3;               // batch
    float bvj[4];
#pragma unroll
    for (int j = 0; j < 4; ++j) bvj[j] = bias[col0 + j * 16 + l15];
    const int colL0 = col0 & 1023;
    if (seg < 2) {
      // stage transposed: p = local col [0,256), m = local row [0,256)
#pragma unroll
      for (int i = 0; i < 4; ++i)
#pragma unroll
        for (int j = 0; j < 4; ++j) {
          const int p = wcn * 64 + j * 16 + l15;
          const int m = wr * 64 + i * 16 + lk * 4;     // aligned 4
          us4 o;
#pragma unroll
          for (int r = 0; r < 4; ++r) o[r] = f2b(acc[i][j][r] + bvj[j]);
          *(us4*)&sc[p * 256 + (((m >> 3) ^ (p & 15)) << 3) + (m & 7)] = o;
        }
      // col reductions (pre-stage values, in-register)
#pragma unroll
      for (int j = 0; j < 4; ++j) {
        const int colL = colL0 + j * 16 + l15;
        float ss = 0.f, sm = 0.f;
#pragma unroll
        for (int i = 0; i < 4; ++i)
#pragma unroll
          for (int r = 0; r < 4; ++r) {
            const float v = acc[i][j][r] + bvj[j];
            ss += v * v; sm += v;
          }
        ss = red4lk(ss);
        if (seg == 0) sm = red4lk(sm);
        if (lk == 0) {
          atomicAdd(&(seg == 0 ? r1 : r3)[(long)b * 1024 + colL], ss);
          if (seg == 0) atomicAdd(&r2[(long)b * 1024 + colL], sm);
        }
      }
      SBAR;
      unsigned short* tp = (seg == 0 ? (unsigned short*)O0 : (unsigned short*)O1)
                           + (long)b * 2097152;        // 1024*2048 per batch
      const int P0 = (bn & 3) * 256;
      const int M0 = (bm & 7) * 256;
#pragma unroll
      for (int it = 0; it < 8; ++it) {
        const int p = it * 32 + (tid >> 5);            // [0,256)
        const int c = lane & 31;
        us8 v = *(const us8*)&sc[p * 256 + ((c ^ (p & 15)) << 3)];
        *(us8*)&tp[(long)(P0 + p) * 2048 + M0 + c * 8] = v;
      }
    } else {
      // V: stage normal layout + row sums
#pragma unroll
      for (int i = 0; i < 4; ++i)
#pragma unroll
        for (int r = 0; r < 4; ++r) {
          const int rl = wr * 64 + i * 16 + lk * 4 + r;   // [0,256)
          float sm = 0.f;
#pragma unroll
          for (int j = 0; j < 4; ++j) {
            const float v = acc[i][j][r] + bvj[j];
            sm += v;
            const int col = wcn * 64 + j * 16 + l15;
            sc[rl * 256 + (((col >> 3) ^ (rl & 15)) << 3) + (col & 7)] = f2b(v);
          }
          sm = red16(sm);
          if (l15 == 0) atomicAdd(&r4[row0 + i * 16 + lk * 4 + r], sm);
        }
      SBAR;
      unsigned short* outp = (unsigned short*)O2;
      const int C0 = (bn & 3) * 256;
#pragma unroll
      for (int it = 0; it < 8; ++it) {
        const int rl = it * 32 + (tid >> 5);
        const int c = lane & 31;
        us8 v = *(const us8*)&sc[rl * 256 + ((c ^ (rl & 15)) << 3)];
        *(us8*)&outp[(long)(bm * 256 + rl) * 1024 + C0 + c * 8] = v;
      }
    }
  }
}

extern "C" void kernel_launch(void* const* d_in, const int* in_sizes, int n_in,
                              void* d_out, int out_size, void* d_ws, size_t ws_size,
                              hipStream_t stream) {
  (void)in_sizes; (void)n_in; (void)out_size;
  const float* x     = (const float*)d_in[0];
  const float* Wq    = (const float*)d_in[1];
  const float* bq    = (const float*)d_in[2];
  const float* Wk    = (const float*)d_in[3];
  const float* bk    = (const float*)d_in[4];
  const float* Wv    = (const float*)d_in[5];
  const float* bv    = (const float*)d_in[6];
  const float* gamma = (const float*)d_in[7];

  // B=16, C=2048, L=D=1024
  const long NE = 16L * 2048 * 1024;
  const long BUF = NE * 2;                    // bytes per bf16 tensor

  char* w = (char*)d_ws;
  unsigned short* QT  = (unsigned short*)(w);            // [16][1024][2048] bf16
  unsigned short* KT  = (unsigned short*)(w + BUF);      // [16][1024][2048] bf16
  unsigned short* Vh  = (unsigned short*)(w + 2 * BUF);  // [32768][1024]
  unsigned short* xh  = (unsigned short*)(w + 3 * BUF);  // live to the end
  unsigned short* S   = (unsigned short*)(w + 4 * BUF);  // [16][1024][1024] (33.5 MB)
  size_t off = 4 * (size_t)BUF + (size_t)BUF / 2 + 4096;
  unsigned short* Wqkvh = (unsigned short*)(w + off); off += 3 * 2097152;  // Wq|Wk|Wv contiguous
  char* accbase = w + off;
  float* pq     = (float*)(w + off); off += 65536;       // col sumsq of Q  (16x1024)
  float* qsum   = (float*)(w + off); off += 65536;       // col sum of Q
  float* pk     = (float*)(w + off); off += 65536;       // col sumsq of K
  float* Vsum   = (float*)(w + off); off += 131072;      // row sum of V    (16x2048)
  float* Srow   = (float*)(w + off); off += 65536;       // row sum of scaled S (16x1024)
  const size_t accbytes = (size_t)(w + off - accbase);
  float* invq   = (float*)(w + off); off += 65536;
  float* invk   = (float*)(w + off); off += 65536;
  float* tailor = (float*)(w + off); off += 65536;
  float* bqkv   = (float*)(w + off); off += 12288;
  if (ws_size < off) return;

  // 0) zero atomic accumulators
  hipMemsetAsync(accbase, 0, accbytes, stream);

  // 1) casts + bias concat
  k_f32_to_bf16<<<dim3((unsigned)(NE / 1024)), 256, 0, stream>>>(x, xh, NE);
  k_f32_to_bf16<<<dim3(1024), 256, 0, stream>>>(Wq, Wqkvh, 1048576);
  k_f32_to_bf16<<<dim3(1024), 256, 0, stream>>>(Wk, Wqkvh + 1048576, 1048576);
  k_f32_to_bf16<<<dim3(1024), 256, 0, stream>>>(Wv, Wqkvh + 2097152, 1048576);
  k_bias_cat<<<dim3(12), 256, 0, stream>>>(bq, bk, bv, bqkv);

  // 2) merged QKV GEMM: M=32768, N=3072, K=1024; Q,K stored transposed + fused reductions
  k_g256<5><<<dim3(12, 128, 1), 1024, 0, stream>>>(
      xh, Wqkvh, QT, KT, Vh, 1024, 0, 0, 0, bqkv,
      pq, qsum, pk, Vsum, nullptr, nullptr, nullptr, nullptr);

  // 3) inverse norms
  k_norms_fin<<<dim3(64), 256, 0, stream>>>(pq, pk, invq, invk);

  // 4) S = invq.(QT x KT^T).invk per batch (M=N=1024, K=2048) + scaled row sums
  k_g256<4><<<dim3(4, 4, 16), 1024, 0, stream>>>(
      QT, KT, S, nullptr, nullptr, 2048, 1024L * 2048, 1024L * 2048, 1024L * 1024,
      nullptr, Srow, invq, invk, nullptr, nullptr, nullptr, nullptr, nullptr);

  // 5) tailor
  k_tailor_fin<<<dim3(64), 256, 0, stream>>>(Srow, invq, qsum, tailor);

  // 6) out = xh + gamma*(Vsum + V x S^T) * tailor   (M=2048/batch, N=1024, K=1024)
  k_g256<1><<<dim3(4, 8, 16), 1024, 0, stream>>>(
      Vh, S, d_out, nullptr, nullptr, 1024, 2048L * 1024, 1024L * 1024, 2048L * 1024,
      nullptr, nullptr, nullptr, nullptr, nullptr, xh, Vsum, tailor, gamma);
}

// Round 15
// 466.952 us; speedup vs baseline: 1.8745x; 1.8745x over previous
//
#include <hip/hip_runtime.h>
#include <cstdint>

#define DEV static __device__ __forceinline__

typedef __attribute__((ext_vector_type(8))) short short8v;     // 8 x bf16 bits
typedef __attribute__((ext_vector_type(4))) float f32x4;
typedef __attribute__((ext_vector_type(4))) float fl4;
typedef __attribute__((ext_vector_type(4))) unsigned short us4;
typedef __attribute__((ext_vector_type(8))) unsigned short us8;

DEV float b2f(unsigned short u) {
  union { unsigned int i; float f; } c; c.i = ((unsigned int)u) << 16; return c.f;
}
DEV unsigned short f2b(float f) {   // RNE float -> bf16 bits
  union { float f; unsigned int i; } c; c.f = f;
  unsigned int u = c.i;
  u += 0x7fffu + ((u >> 16) & 1u);
  return (unsigned short)(u >> 16);
}

DEV void gload16(const void* g, void* l) {  // async global->LDS, 16B/lane
  __builtin_amdgcn_global_load_lds(
      (const __attribute__((address_space(1))) unsigned int*)g,
      (__attribute__((address_space(3))) unsigned int*)l, 16, 0, 0);
}

DEV float red16(float v) {  // reduce across 16 lanes sharing lk (xor low 4 bits)
  v += __shfl_xor(v, 1); v += __shfl_xor(v, 2);
  v += __shfl_xor(v, 4); v += __shfl_xor(v, 8);
  return v;
}
DEV float red4lk(float v) { // reduce across the 4 lk groups (xor bits 4,5)
  v += __shfl_xor(v, 16); v += __shfl_xor(v, 32);
  return v;
}

// ---------------- elementwise f32 -> bf16 ----------------
__global__ __launch_bounds__(256) void k_f32_to_bf16(const float* __restrict__ src,
                                                     unsigned short* __restrict__ dst, long n) {
  long i = ((long)blockIdx.x * 256 + threadIdx.x) * 4;
  if (i >= n) return;
  fl4 v = *(const fl4*)(src + i);
  us4 o;
  o[0] = f2b(v[0]); o[1] = f2b(v[1]); o[2] = f2b(v[2]); o[3] = f2b(v[3]);
  *(us4*)(dst + i) = o;
}

// ---------------- cast Wq|Wk|Wv into one contiguous bf16 buffer ----------------
__global__ __launch_bounds__(256) void k_wcast(const float* __restrict__ wq,
                                               const float* __restrict__ wk,
                                               const float* __restrict__ wv,
                                               unsigned short* __restrict__ dst) {
  const long i = ((long)blockIdx.x * 256 + threadIdx.x) * 4;   // [0, 3M)
  const int seg = (int)(i >> 20);                              // 1M elems per W
  const float* s = seg == 0 ? wq : (seg == 1 ? wk : wv);
  fl4 v = *(const fl4*)(s + (i & 1048575));
  us4 o;
  o[0] = f2b(v[0]); o[1] = f2b(v[1]); o[2] = f2b(v[2]); o[3] = f2b(v[3]);
  *(us4*)(dst + i) = o;
}

// ---------------- concat biases into 3072-float buffer ----------------
__global__ __launch_bounds__(256) void k_bias_cat(const float* __restrict__ bq,
                                                  const float* __restrict__ bk,
                                                  const float* __restrict__ bv,
                                                  float* __restrict__ o) {
  const int t = blockIdx.x * 256 + threadIdx.x;   // 3072
  o[t] = t < 1024 ? bq[t] : (t < 2048 ? bk[t - 1024] : bv[t - 2048]);
}

// ---------------- finalize inverse norms ----------------
__global__ __launch_bounds__(256) void k_norms_fin(const float* __restrict__ pq,
                                                   const float* __restrict__ pk,
                                                   float* __restrict__ invq, float* __restrict__ invk) {
  const int gid = blockIdx.x * 256 + threadIdx.x;   // 16384
  invq[gid] = rsqrtf(pq[gid]);
  invk[gid] = rsqrtf(pk[gid]);
}

// ---------------- finalize tailor: 1/(L + rowsum(S) + eps*invq*colsum(Q)) ----------------
__global__ __launch_bounds__(256) void k_tailor_fin(const float* __restrict__ Srow,
                                                    const float* __restrict__ invq,
                                                    const float* __restrict__ qsum,
                                                    float* __restrict__ tailor) {
  const int gid = blockIdx.x * 256 + threadIdx.x;   // 16384
  tailor[gid] = 1.0f / (1024.0f + Srow[gid] + 1e-6f * invq[gid] * qsum[gid]);
}

#define MFMA_BF16 __builtin_amdgcn_mfma_f32_16x16x32_bf16
#define SBAR   __builtin_amdgcn_s_barrier()

// ================= 8-WAVE variant (R12-verbatim, best for S & final GEMMs) =============
// 256x256 NT GEMM, BK=32, 8 waves (2Mx4N, 128x64 each), free-run interior:
// 4 LDS K-tile buffers (128 KiB); stage t+2 at t; counted vmcnt(4); barrier every 2nd
// tile. LDS chunk-swizzle (0-conflict) + XCD swizzle + LDS-roundtrip epilogues (R11).
// EPI 1: final fused fp32 epilogue.  EPI 4: scaled-S + row sums.
template<int EPI>
__global__ __launch_bounds__(512)
void k_g8(const unsigned short* __restrict__ A,
          const unsigned short* __restrict__ Bt,
          void* __restrict__ O0,
          int K, long sA, long sB, long sC,
          float* __restrict__ r1, float* __restrict__ r2, float* __restrict__ r3,
          const unsigned short* __restrict__ xh,
          const float* __restrict__ Vsum,
          const float* __restrict__ tailor,
          const float* __restrict__ gptr) {
  __shared__ __align__(16) unsigned short LDSU[65536];

  const int tid = threadIdx.x;
  const int wv = tid >> 6, lane = tid & 63;
  const int wr = wv >> 2, wcn = wv & 3;
  const int l15 = lane & 15, lk = lane >> 4;

  const int nx = gridDim.x;
  const int nwg = nx * gridDim.y;
  const int lin = blockIdx.y * nx + blockIdx.x;
  const int cpx = nwg >> 3;
  const int wg = (lin & 7) * cpx + (lin >> 3);
  const int bn = wg % nx;
  const int bm = wg / nx;
  const int bz = blockIdx.z;

  const unsigned short* Ab = A + (long)bz * sA + (long)bm * 256 * K;
  const unsigned short* Bb = Bt + (long)bz * sB + (long)bn * 256 * K;

  const int scsw = (tid & 3) ^ ((tid >> 3) & 3);
  const long gOff = (long)(tid >> 2) * K + (long)scsw * 8;
  const int ldsb = wv * 512;

  const int rdsw = (lk ^ ((l15 >> 1) & 3)) * 8;
  const int abase = (wr * 128 + l15) * 32;
  const int bbase = (wcn * 64 + l15) * 32;

  f32x4 acc[8][4];
#pragma unroll
  for (int i = 0; i < 8; ++i)
#pragma unroll
    for (int j = 0; j < 4; ++j) acc[i][j] = (f32x4){0.f, 0.f, 0.f, 0.f};

#define STAGE8(T, BUF)                                                       \
  {                                                                          \
    const long kb = (long)(T) * 32;                                          \
    unsigned short* Asb = LDSU + (BUF) * 8192;                               \
    unsigned short* Bsb = LDSU + 32768 + (BUF) * 8192;                       \
    gload16(Ab + kb + gOff,            &Asb[ldsb]);                          \
    gload16(Ab + kb + gOff + 128L * K, &Asb[4096 + ldsb]);                   \
    gload16(Bb + kb + gOff,            &Bsb[ldsb]);                          \
    gload16(Bb + kb + gOff + 128L * K, &Bsb[4096 + ldsb]);                   \
  }

  STAGE8(0, 0)
  STAGE8(1, 1)

  const int NT = K >> 5;
  for (int t = 0; t < NT; ++t) {
    if (t < NT - 1) { asm volatile("s_waitcnt vmcnt(4)" ::: "memory"); }
    else            { asm volatile("s_waitcnt vmcnt(0)" ::: "memory"); }
    if ((t & 1) == 0) SBAR;
    if (t + 2 < NT) STAGE8(t + 2, (t + 2) & 3)

    const unsigned short* Asc = LDSU + (t & 3) * 8192;
    const unsigned short* Bsc = LDSU + 32768 + (t & 3) * 8192;
    short8v Bf[4], Af[8];
#pragma unroll
    for (int j = 0; j < 4; ++j)
      Bf[j] = *(const short8v*)&Bsc[bbase + j * 512 + rdsw];
#pragma unroll
    for (int i = 0; i < 8; ++i)
      Af[i] = *(const short8v*)&Asc[abase + i * 512 + rdsw];

    __builtin_amdgcn_s_setprio(1);
#pragma unroll
    for (int i = 0; i < 8; ++i)
#pragma unroll
      for (int j = 0; j < 4; ++j)
        acc[i][j] = MFMA_BF16(Af[i], Bf[j], acc[i][j], 0, 0, 0);
    __builtin_amdgcn_s_setprio(0);
  }
#undef STAGE8
  SBAR;

  const int row0 = bm * 256 + wr * 128;
  const int col0 = bn * 256 + wcn * 64;
  unsigned short* sc = LDSU;
  float* scf = (float*)LDSU;

  if constexpr (EPI == 1) {
    float* Cb = (float*)O0 + (long)bz * sC;
    const float g = gptr[0];
#pragma unroll
    for (int h = 0; h < 2; ++h) {
      if (wr == h) {
#pragma unroll
        for (int i = 0; i < 8; ++i)
#pragma unroll
          for (int j = 0; j < 4; ++j) {
            const int col = wcn * 64 + j * 16 + l15;
            const int cc = col >> 2, c3 = col & 3;
#pragma unroll
            for (int r = 0; r < 4; ++r) {
              const int rl = i * 16 + lk * 4 + r;
              scf[rl * 256 + ((cc ^ (rl & 15)) << 2) + c3] = acc[i][j][r];
            }
          }
      }
      SBAR;
#pragma unroll
      for (int it = 0; it < 16; ++it) {
        const int rl = it * 8 + wv;
        const int rg = bm * 256 + h * 128 + rl;
        const int c = lane;
        fl4 a4 = *(const fl4*)&scf[rl * 256 + ((c ^ (rl & 15)) << 2)];
        const int cg = bn * 256 + c * 4;
        us4 xv = *(const us4*)&xh[((long)bz * 2048 + rg) * 1024 + cg];
        fl4 tl = *(const fl4*)&tailor[bz * 1024 + cg];
        const float vs = Vsum[bz * 2048 + rg];
        fl4 o;
#pragma unroll
        for (int q = 0; q < 4; ++q) o[q] = b2f(xv[q]) + g * ((vs + a4[q]) * tl[q]);
        *(fl4*)&Cb[(long)rg * 1024 + cg] = o;
      }
      if (h == 0) SBAR;
    }
  } else {  // EPI == 4
    unsigned short* Cb = (unsigned short*)O0 + (long)bz * sC;
    float ivk[4];
#pragma unroll
    for (int j = 0; j < 4; ++j) ivk[j] = r3[bz * 1024 + col0 + j * 16 + l15];
#pragma unroll
    for (int i = 0; i < 8; ++i) {
      float ivq[4];
#pragma unroll
      for (int r = 0; r < 4; ++r) ivq[r] = r2[bz * 1024 + row0 + i * 16 + lk * 4 + r];
#pragma unroll
      for (int r = 0; r < 4; ++r) {
        const int rl = wr * 128 + i * 16 + lk * 4 + r;
        float sm = 0.f;
#pragma unroll
        for (int j = 0; j < 4; ++j) {
          const float v = acc[i][j][r] * ivq[r] * ivk[j];
          sm += v;
          const int col = wcn * 64 + j * 16 + l15;
          sc[rl * 256 + (((col >> 3) ^ (rl & 15)) << 3) + (col & 7)] = f2b(v);
        }
        sm = red16(sm);
        if (l15 == 0) atomicAdd(&r1[(long)bz * 1024 + row0 + i * 16 + lk * 4 + r], sm);
      }
    }
    SBAR;
#pragma unroll
    for (int it = 0; it < 16; ++it) {
      const int rl = it * 16 + wv * 2 + (lane >> 5);
      const int c = lane & 31;
      us8 v = *(const us8*)&sc[rl * 256 + ((c ^ (rl & 15)) << 3)];
      *(us8*)&Cb[(long)(bm * 256 + rl) * 1024 + bn * 256 + c * 8] = v;
    }
  }
}

// ================= 16-WAVE variant (R13-verbatim, best for merged QKV) =================
// 256x256 NT GEMM, BK=32, 16 waves (4Mx4N, 64x64 each): 4 LDS buffers, stage t+2,
// counted vmcnt(2), barrier per tile (sound staging visibility). Q/K stored TRANSPOSED
// via LDS-roundtrip + fused col reductions; V normal + row sums.
__global__ __launch_bounds__(1024, 4)
void k_g16qkv(const unsigned short* __restrict__ A,
              const unsigned short* __restrict__ Bt,
              void* __restrict__ O0, void* __restrict__ O1, void* __restrict__ O2,
              int K,
              const float* __restrict__ bias,
              float* __restrict__ r1, float* __restrict__ r2,
              float* __restrict__ r3, float* __restrict__ r4) {
  __shared__ __align__(16) unsigned short LDSU[65536];

  const int tid = threadIdx.x;
  const int wv = tid >> 6, lane = tid & 63;
  const int wr = wv >> 2, wcn = wv & 3;
  const int l15 = lane & 15, lk = lane >> 4;

  const int nx = gridDim.x;
  const int nwg = nx * gridDim.y;
  const int lin = blockIdx.y * nx + blockIdx.x;
  const int cpx = nwg >> 3;
  const int wg = (lin & 7) * cpx + (lin >> 3);
  const int bn = wg % nx;
  const int bm = wg / nx;

  const unsigned short* Ab = A + (long)bm * 256 * K;
  const unsigned short* Bb = Bt + (long)bn * 256 * K;

  const int scsw = (tid & 3) ^ ((tid >> 3) & 3);
  const long gOff = (long)(tid >> 2) * K + (long)scsw * 8;
  const int ldsb = wv * 512;

  const int rdsw = (lk ^ ((l15 >> 1) & 3)) * 8;
  const int abase = (wr * 64 + l15) * 32;
  const int bbase = (wcn * 64 + l15) * 32;

  f32x4 acc[4][4];
#pragma unroll
  for (int i = 0; i < 4; ++i)
#pragma unroll
    for (int j = 0; j < 4; ++j) acc[i][j] = (f32x4){0.f, 0.f, 0.f, 0.f};

#define STAGE16(T, BUF)                                                      \
  {                                                                          \
    const long kb = (long)(T) * 32;                                          \
    gload16(Ab + kb + gOff, LDSU + (BUF) * 8192 + ldsb);                     \
    gload16(Bb + kb + gOff, LDSU + 32768 + (BUF) * 8192 + ldsb);             \
  }

  STAGE16(0, 0)
  STAGE16(1, 1)

  const int NT = K >> 5;
  for (int t = 0; t < NT; ++t) {
    if (t < NT - 1) { asm volatile("s_waitcnt vmcnt(2)" ::: "memory"); }
    else            { asm volatile("s_waitcnt vmcnt(0)" ::: "memory"); }
    SBAR;
    if (t + 2 < NT) STAGE16(t + 2, (t + 2) & 3)

    const unsigned short* Asc = LDSU + (t & 3) * 8192;
    const unsigned short* Bsc = LDSU + 32768 + (t & 3) * 8192;
    short8v Bf[4], Af[4];
#pragma unroll
    for (int j = 0; j < 4; ++j)
      Bf[j] = *(const short8v*)&Bsc[bbase + j * 512 + rdsw];
#pragma unroll
    for (int i = 0; i < 4; ++i)
      Af[i] = *(const short8v*)&Asc[abase + i * 512 + rdsw];

    __builtin_amdgcn_s_setprio(1);
#pragma unroll
    for (int i = 0; i < 4; ++i)
#pragma unroll
      for (int j = 0; j < 4; ++j)
        acc[i][j] = MFMA_BF16(Af[i], Bf[j], acc[i][j], 0, 0, 0);
    __builtin_amdgcn_s_setprio(0);
  }
#undef STAGE16
  SBAR;

  const int row0 = bm * 256 + wr * 64;
  const int col0 = bn * 256 + wcn * 64;
  unsigned short* sc = LDSU;

  const int seg = bn >> 2;             // 0=Q, 1=K, 2=V
  const int b = bm >> 3;               // batch
  float bvj[4];
#pragma unroll
  for (int j = 0; j < 4; ++j) bvj[j] = bias[col0 + j * 16 + l15];
  const int colL0 = col0 & 1023;
  if (seg < 2) {
#pragma unroll
    for (int i = 0; i < 4; ++i)
#pragma unroll
      for (int j = 0; j < 4; ++j) {
        const int p = wcn * 64 + j * 16 + l15;
        const int m = wr * 64 + i * 16 + lk * 4;
        us4 o;
#pragma unroll
        for (int r = 0; r < 4; ++r) o[r] = f2b(acc[i][j][r] + bvj[j]);
        *(us4*)&sc[p * 256 + (((m >> 3) ^ (p & 15)) << 3) + (m & 7)] = o;
      }
#pragma unroll
    for (int j = 0; j < 4; ++j) {
      const int colL = colL0 + j * 16 + l15;
      float ss = 0.f, sm = 0.f;
#pragma unroll
      for (int i = 0; i < 4; ++i)
#pragma unroll
        for (int r = 0; r < 4; ++r) {
          const float v = acc[i][j][r] + bvj[j];
          ss += v * v; sm += v;
        }
      ss = red4lk(ss);
      if (seg == 0) sm = red4lk(sm);
      if (lk == 0) {
        atomicAdd(&(seg == 0 ? r1 : r3)[(long)b * 1024 + colL], ss);
        if (seg == 0) atomicAdd(&r2[(long)b * 1024 + colL], sm);
      }
    }
    SBAR;
    unsigned short* tp = (seg == 0 ? (unsigned short*)O0 : (unsigned short*)O1)
                         + (long)b * 2097152;
    const int P0 = (bn & 3) * 256;
    const int M0 = (bm & 7) * 256;
#pragma unroll
    for (int it = 0; it < 8; ++it) {
      const int p = it * 32 + (tid >> 5);
      const int c = lane & 31;
      us8 v = *(const us8*)&sc[p * 256 + ((c ^ (p & 15)) << 3)];
      *(us8*)&tp[(long)(P0 + p) * 2048 + M0 + c * 8] = v;
    }
  } else {
#pragma unroll
    for (int i = 0; i < 4; ++i)
#pragma unroll
      for (int r = 0; r < 4; ++r) {
        const int rl = wr * 64 + i * 16 + lk * 4 + r;
        float sm = 0.f;
#pragma unroll
        for (int j = 0; j < 4; ++j) {
          const float v = acc[i][j][r] + bvj[j];
          sm += v;
          const int col = wcn * 64 + j * 16 + l15;
          sc[rl * 256 + (((col >> 3) ^ (rl & 15)) << 3) + (col & 7)] = f2b(v);
        }
        sm = red16(sm);
        if (l15 == 0) atomicAdd(&r4[row0 + i * 16 + lk * 4 + r], sm);
      }
    SBAR;
    unsigned short* outp = (unsigned short*)O2;
    const int C0 = (bn & 3) * 256;
#pragma unroll
    for (int it = 0; it < 8; ++it) {
      const int rl = it * 32 + (tid >> 5);
      const int c = lane & 31;
      us8 v = *(const us8*)&sc[rl * 256 + ((c ^ (rl & 15)) << 3)];
      *(us8*)&outp[(long)(bm * 256 + rl) * 1024 + C0 + c * 8] = v;
    }
  }
}

extern "C" void kernel_launch(void* const* d_in, const int* in_sizes, int n_in,
                              void* d_out, int out_size, void* d_ws, size_t ws_size,
                              hipStream_t stream) {
  (void)in_sizes; (void)n_in; (void)out_size;
  const float* x     = (const float*)d_in[0];
  const float* Wq    = (const float*)d_in[1];
  const float* bq    = (const float*)d_in[2];
  const float* Wk    = (const float*)d_in[3];
  const float* bk    = (const float*)d_in[4];
  const float* Wv    = (const float*)d_in[5];
  const float* bv    = (const float*)d_in[6];
  const float* gamma = (const float*)d_in[7];

  // B=16, C=2048, L=D=1024
  const long NE = 16L * 2048 * 1024;
  const long BUF = NE * 2;                    // bytes per bf16 tensor

  char* w = (char*)d_ws;
  unsigned short* QT  = (unsigned short*)(w);            // [16][1024][2048] bf16
  unsigned short* KT  = (unsigned short*)(w + BUF);      // [16][1024][2048] bf16
  unsigned short* Vh  = (unsigned short*)(w + 2 * BUF);  // [32768][1024]
  unsigned short* xh  = (unsigned short*)(w + 3 * BUF);  // live to the end
  unsigned short* S   = (unsigned short*)(w + 4 * BUF);  // [16][1024][1024] (33.5 MB)
  size_t off = 4 * (size_t)BUF + (size_t)BUF / 2 + 4096;
  unsigned short* Wqkvh = (unsigned short*)(w + off); off += 3 * 2097152;  // Wq|Wk|Wv
  char* accbase = w + off;
  float* pq     = (float*)(w + off); off += 65536;       // col sumsq of Q  (16x1024)
  float* qsum   = (float*)(w + off); off += 65536;       // col sum of Q
  float* pk     = (float*)(w + off); off += 65536;       // col sumsq of K
  float* Vsum   = (float*)(w + off); off += 131072;      // row sum of V    (16x2048)
  float* Srow   = (float*)(w + off); off += 65536;       // row sum of scaled S (16x1024)
  const size_t accbytes = (size_t)(w + off - accbase);
  float* invq   = (float*)(w + off); off += 65536;
  float* invk   = (float*)(w + off); off += 65536;
  float* tailor = (float*)(w + off); off += 65536;
  float* bqkv   = (float*)(w + off); off += 12288;
  if (ws_size < off) return;

  // 0) zero atomic accumulators
  hipMemsetAsync(accbase, 0, accbytes, stream);

  // 1) casts + bias concat
  k_f32_to_bf16<<<dim3((unsigned)(NE / 1024)), 256, 0, stream>>>(x, xh, NE);
  k_wcast<<<dim3(3072), 256, 0, stream>>>(Wq, Wk, Wv, Wqkvh);
  k_bias_cat<<<dim3(12), 256, 0, stream>>>(bq, bk, bv, bqkv);

  // 2) merged QKV GEMM (16-wave): M=32768, N=3072, K=1024; Q,K transposed + reductions
  k_g16qkv<<<dim3(12, 128, 1), 1024, 0, stream>>>(
      xh, Wqkvh, QT, KT, Vh, 1024, bqkv, pq, qsum, pk, Vsum);

  // 3) inverse norms
  k_norms_fin<<<dim3(64), 256, 0, stream>>>(pq, pk, invq, invk);

  // 4) S = invq.(QT x KT^T).invk per batch (8-wave; M=N=1024, K=2048) + scaled row sums
  k_g8<4><<<dim3(4, 4, 16), 512, 0, stream>>>(
      QT, KT, S, 2048, 1024L * 2048, 1024L * 2048, 1024L * 1024,
      Srow, invq, invk, nullptr, nullptr, nullptr, nullptr);

  // 5) tailor
  k_tailor_fin<<<dim3(64), 256, 0, stream>>>(Srow, invq, qsum, tailor);

  // 6) out = xh + gamma*(Vsum + V x S^T) * tailor   (8-wave; M=2048/batch, N=1024, K=1024)
  k_g8<1><<<dim3(4, 8, 16), 512, 0, stream>>>(
      Vh, S, d_out, 1024, 2048L * 1024, 1024L * 1024, 2048L * 1024,
      nullptr, nullptr, nullptr, xh, Vsum, tailor, gamma);
}

// Round 16
// 462.893 us; speedup vs baseline: 1.8909x; 1.0088x over previous
//
#include <hip/hip_runtime.h>
#include <cstdint>

#define DEV static __device__ __forceinline__

typedef __attribute__((ext_vector_type(8))) short short8v;     // 8 x bf16 bits
typedef __attribute__((ext_vector_type(4))) float f32x4;
typedef __attribute__((ext_vector_type(4))) float fl4;
typedef __attribute__((ext_vector_type(4))) unsigned short us4;
typedef __attribute__((ext_vector_type(8))) unsigned short us8;

DEV float b2f(unsigned short u) {
  union { unsigned int i; float f; } c; c.i = ((unsigned int)u) << 16; return c.f;
}
DEV unsigned short f2b(float f) {   // RNE float -> bf16 bits
  union { float f; unsigned int i; } c; c.f = f;
  unsigned int u = c.i;
  u += 0x7fffu + ((u >> 16) & 1u);
  return (unsigned short)(u >> 16);
}

DEV void gload16(const void* g, void* l) {  // async global->LDS, 16B/lane
  __builtin_amdgcn_global_load_lds(
      (const __attribute__((address_space(1))) unsigned int*)g,
      (__attribute__((address_space(3))) unsigned int*)l, 16, 0, 0);
}

DEV float red16(float v) {  // reduce across 16 lanes sharing lk (xor low 4 bits)
  v += __shfl_xor(v, 1); v += __shfl_xor(v, 2);
  v += __shfl_xor(v, 4); v += __shfl_xor(v, 8);
  return v;
}
DEV float red4lk(float v) { // reduce across the 4 lk groups (xor bits 4,5)
  v += __shfl_xor(v, 16); v += __shfl_xor(v, 32);
  return v;
}

// ---------------- elementwise f32 -> bf16 ----------------
__global__ __launch_bounds__(256) void k_f32_to_bf16(const float* __restrict__ src,
                                                     unsigned short* __restrict__ dst, long n) {
  long i = ((long)blockIdx.x * 256 + threadIdx.x) * 4;
  if (i >= n) return;
  fl4 v = *(const fl4*)(src + i);
  us4 o;
  o[0] = f2b(v[0]); o[1] = f2b(v[1]); o[2] = f2b(v[2]); o[3] = f2b(v[3]);
  *(us4*)(dst + i) = o;
}

// ---------------- cast Wq|Wk|Wv into one contiguous bf16 buffer ----------------
__global__ __launch_bounds__(256) void k_wcast(const float* __restrict__ wq,
                                               const float* __restrict__ wk,
                                               const float* __restrict__ wv,
                                               unsigned short* __restrict__ dst) {
  const long i = ((long)blockIdx.x * 256 + threadIdx.x) * 4;   // [0, 3M)
  const int seg = (int)(i >> 20);                              // 1M elems per W
  const float* s = seg == 0 ? wq : (seg == 1 ? wk : wv);
  fl4 v = *(const fl4*)(s + (i & 1048575));
  us4 o;
  o[0] = f2b(v[0]); o[1] = f2b(v[1]); o[2] = f2b(v[2]); o[3] = f2b(v[3]);
  *(us4*)(dst + i) = o;
}

// ---------------- concat biases into 3072-float buffer ----------------
__global__ __launch_bounds__(256) void k_bias_cat(const float* __restrict__ bq,
                                                  const float* __restrict__ bk,
                                                  const float* __restrict__ bv,
                                                  float* __restrict__ o) {
  const int t = blockIdx.x * 256 + threadIdx.x;   // 3072
  o[t] = t < 1024 ? bq[t] : (t < 2048 ? bk[t - 1024] : bv[t - 2048]);
}

// ---------------- finalize inverse norms ----------------
__global__ __launch_bounds__(256) void k_norms_fin(const float* __restrict__ pq,
                                                   const float* __restrict__ pk,
                                                   float* __restrict__ invq, float* __restrict__ invk) {
  const int gid = blockIdx.x * 256 + threadIdx.x;   // 16384
  invq[gid] = rsqrtf(pq[gid]);
  invk[gid] = rsqrtf(pk[gid]);
}

// ---------------- finalize tailor: 1/(L + rowsum(S) + eps*invq*colsum(Q)) ----------------
__global__ __launch_bounds__(256) void k_tailor_fin(const float* __restrict__ Srow,
                                                    const float* __restrict__ invq,
                                                    const float* __restrict__ qsum,
                                                    float* __restrict__ tailor) {
  const int gid = blockIdx.x * 256 + threadIdx.x;   // 16384
  tailor[gid] = 1.0f / (1024.0f + Srow[gid] + 1e-6f * invq[gid] * qsum[gid]);
}

#define MFMA_BF16 __builtin_amdgcn_mfma_f32_16x16x32_bf16
#define SBAR   __builtin_amdgcn_s_barrier()

// ================= 8-WAVE variant (R12-verbatim, best for S & final GEMMs) =============
template<int EPI>
__global__ __launch_bounds__(512)
void k_g8(const unsigned short* __restrict__ A,
          const unsigned short* __restrict__ Bt,
          void* __restrict__ O0,
          int K, long sA, long sB, long sC,
          float* __restrict__ r1, float* __restrict__ r2, float* __restrict__ r3,
          const unsigned short* __restrict__ xh,
          const float* __restrict__ Vsum,
          const float* __restrict__ tailor,
          const float* __restrict__ gptr) {
  __shared__ __align__(16) unsigned short LDSU[65536];

  const int tid = threadIdx.x;
  const int wv = tid >> 6, lane = tid & 63;
  const int wr = wv >> 2, wcn = wv & 3;
  const int l15 = lane & 15, lk = lane >> 4;

  const int nx = gridDim.x;
  const int nwg = nx * gridDim.y;
  const int lin = blockIdx.y * nx + blockIdx.x;
  const int cpx = nwg >> 3;
  const int wg = (lin & 7) * cpx + (lin >> 3);
  const int bn = wg % nx;
  const int bm = wg / nx;
  const int bz = blockIdx.z;

  const unsigned short* Ab = A + (long)bz * sA + (long)bm * 256 * K;
  const unsigned short* Bb = Bt + (long)bz * sB + (long)bn * 256 * K;

  const int scsw = (tid & 3) ^ ((tid >> 3) & 3);
  const long gOff = (long)(tid >> 2) * K + (long)scsw * 8;
  const int ldsb = wv * 512;

  const int rdsw = (lk ^ ((l15 >> 1) & 3)) * 8;
  const int abase = (wr * 128 + l15) * 32;
  const int bbase = (wcn * 64 + l15) * 32;

  f32x4 acc[8][4];
#pragma unroll
  for (int i = 0; i < 8; ++i)
#pragma unroll
    for (int j = 0; j < 4; ++j) acc[i][j] = (f32x4){0.f, 0.f, 0.f, 0.f};

#define STAGE8(T, BUF)                                                       \
  {                                                                          \
    const long kb = (long)(T) * 32;                                          \
    unsigned short* Asb = LDSU + (BUF) * 8192;                               \
    unsigned short* Bsb = LDSU + 32768 + (BUF) * 8192;                       \
    gload16(Ab + kb + gOff,            &Asb[ldsb]);                          \
    gload16(Ab + kb + gOff + 128L * K, &Asb[4096 + ldsb]);                   \
    gload16(Bb + kb + gOff,            &Bsb[ldsb]);                          \
    gload16(Bb + kb + gOff + 128L * K, &Bsb[4096 + ldsb]);                   \
  }

  STAGE8(0, 0)
  STAGE8(1, 1)

  const int NT = K >> 5;
  for (int t = 0; t < NT; ++t) {
    if (t < NT - 1) { asm volatile("s_waitcnt vmcnt(4)" ::: "memory"); }
    else            { asm volatile("s_waitcnt vmcnt(0)" ::: "memory"); }
    if ((t & 1) == 0) SBAR;
    if (t + 2 < NT) STAGE8(t + 2, (t + 2) & 3)

    const unsigned short* Asc = LDSU + (t & 3) * 8192;
    const unsigned short* Bsc = LDSU + 32768 + (t & 3) * 8192;
    short8v Bf[4], Af[8];
#pragma unroll
    for (int j = 0; j < 4; ++j)
      Bf[j] = *(const short8v*)&Bsc[bbase + j * 512 + rdsw];
#pragma unroll
    for (int i = 0; i < 8; ++i)
      Af[i] = *(const short8v*)&Asc[abase + i * 512 + rdsw];

    __builtin_amdgcn_s_setprio(1);
#pragma unroll
    for (int i = 0; i < 8; ++i)
#pragma unroll
      for (int j = 0; j < 4; ++j)
        acc[i][j] = MFMA_BF16(Af[i], Bf[j], acc[i][j], 0, 0, 0);
    __builtin_amdgcn_s_setprio(0);
  }
#undef STAGE8
  SBAR;

  const int row0 = bm * 256 + wr * 128;
  const int col0 = bn * 256 + wcn * 64;
  unsigned short* sc = LDSU;
  float* scf = (float*)LDSU;

  if constexpr (EPI == 1) {
    float* Cb = (float*)O0 + (long)bz * sC;
    const float g = gptr[0];
#pragma unroll
    for (int h = 0; h < 2; ++h) {
      if (wr == h) {
#pragma unroll
        for (int i = 0; i < 8; ++i)
#pragma unroll
          for (int j = 0; j < 4; ++j) {
            const int col = wcn * 64 + j * 16 + l15;
            const int cc = col >> 2, c3 = col & 3;
#pragma unroll
            for (int r = 0; r < 4; ++r) {
              const int rl = i * 16 + lk * 4 + r;
              scf[rl * 256 + ((cc ^ (rl & 15)) << 2) + c3] = acc[i][j][r];
            }
          }
      }
      SBAR;
#pragma unroll
      for (int it = 0; it < 16; ++it) {
        const int rl = it * 8 + wv;
        const int rg = bm * 256 + h * 128 + rl;
        const int c = lane;
        fl4 a4 = *(const fl4*)&scf[rl * 256 + ((c ^ (rl & 15)) << 2)];
        const int cg = bn * 256 + c * 4;
        us4 xv = *(const us4*)&xh[((long)bz * 2048 + rg) * 1024 + cg];
        fl4 tl = *(const fl4*)&tailor[bz * 1024 + cg];
        const float vs = Vsum[bz * 2048 + rg];
        fl4 o;
#pragma unroll
        for (int q = 0; q < 4; ++q) o[q] = b2f(xv[q]) + g * ((vs + a4[q]) * tl[q]);
        *(fl4*)&Cb[(long)rg * 1024 + cg] = o;
      }
      if (h == 0) SBAR;
    }
  } else {  // EPI == 4
    unsigned short* Cb = (unsigned short*)O0 + (long)bz * sC;
    float ivk[4];
#pragma unroll
    for (int j = 0; j < 4; ++j) ivk[j] = r3[bz * 1024 + col0 + j * 16 + l15];
#pragma unroll
    for (int i = 0; i < 8; ++i) {
      float ivq[4];
#pragma unroll
      for (int r = 0; r < 4; ++r) ivq[r] = r2[bz * 1024 + row0 + i * 16 + lk * 4 + r];
#pragma unroll
      for (int r = 0; r < 4; ++r) {
        const int rl = wr * 128 + i * 16 + lk * 4 + r;
        float sm = 0.f;
#pragma unroll
        for (int j = 0; j < 4; ++j) {
          const float v = acc[i][j][r] * ivq[r] * ivk[j];
          sm += v;
          const int col = wcn * 64 + j * 16 + l15;
          sc[rl * 256 + (((col >> 3) ^ (rl & 15)) << 3) + (col & 7)] = f2b(v);
        }
        sm = red16(sm);
        if (l15 == 0) atomicAdd(&r1[(long)bz * 1024 + row0 + i * 16 + lk * 4 + r], sm);
      }
    }
    SBAR;
#pragma unroll
    for (int it = 0; it < 16; ++it) {
      const int rl = it * 16 + wv * 2 + (lane >> 5);
      const int c = lane & 31;
      us8 v = *(const us8*)&sc[rl * 256 + ((c ^ (rl & 15)) << 3)];
      *(us8*)&Cb[(long)(bm * 256 + rl) * 1024 + bn * 256 + c * 8] = v;
    }
  }
}

// ================= 16-WAVE variant (R13 + R12's barrier relaxation) ====================
// 256x256 NT GEMM, BK=32, 16 waves (4Mx4N, 64x64 each): 4 LDS buffers, stage t+2,
// counted vmcnt(2), s_barrier EVERY 2ND TILE (this round's single change vs R15).
// Soundness: stage(t) is issued 2 tiles (~2600 cyc) before first read; own vmcnt(2)
// drains own lanes; cross-wave skew bounded to 1 tile by the even-tile barrier — same
// argument R12 validated over 4 passing benches on the 8-wave kernel.
__global__ __launch_bounds__(1024, 4)
void k_g16qkv(const unsigned short* __restrict__ A,
              const unsigned short* __restrict__ Bt,
              void* __restrict__ O0, void* __restrict__ O1, void* __restrict__ O2,
              int K,
              const float* __restrict__ bias,
              float* __restrict__ r1, float* __restrict__ r2,
              float* __restrict__ r3, float* __restrict__ r4) {
  __shared__ __align__(16) unsigned short LDSU[65536];

  const int tid = threadIdx.x;
  const int wv = tid >> 6, lane = tid & 63;
  const int wr = wv >> 2, wcn = wv & 3;
  const int l15 = lane & 15, lk = lane >> 4;

  const int nx = gridDim.x;
  const int nwg = nx * gridDim.y;
  const int lin = blockIdx.y * nx + blockIdx.x;
  const int cpx = nwg >> 3;
  const int wg = (lin & 7) * cpx + (lin >> 3);
  const int bn = wg % nx;
  const int bm = wg / nx;

  const unsigned short* Ab = A + (long)bm * 256 * K;
  const unsigned short* Bb = Bt + (long)bn * 256 * K;

  const int scsw = (tid & 3) ^ ((tid >> 3) & 3);
  const long gOff = (long)(tid >> 2) * K + (long)scsw * 8;
  const int ldsb = wv * 512;

  const int rdsw = (lk ^ ((l15 >> 1) & 3)) * 8;
  const int abase = (wr * 64 + l15) * 32;
  const int bbase = (wcn * 64 + l15) * 32;

  f32x4 acc[4][4];
#pragma unroll
  for (int i = 0; i < 4; ++i)
#pragma unroll
    for (int j = 0; j < 4; ++j) acc[i][j] = (f32x4){0.f, 0.f, 0.f, 0.f};

#define STAGE16(T, BUF)                                                      \
  {                                                                          \
    const long kb = (long)(T) * 32;                                          \
    gload16(Ab + kb + gOff, LDSU + (BUF) * 8192 + ldsb);                     \
    gload16(Bb + kb + gOff, LDSU + 32768 + (BUF) * 8192 + ldsb);             \
  }

  STAGE16(0, 0)
  STAGE16(1, 1)

  const int NT = K >> 5;
  for (int t = 0; t < NT; ++t) {
    if (t < NT - 1) { asm volatile("s_waitcnt vmcnt(2)" ::: "memory"); }
    else            { asm volatile("s_waitcnt vmcnt(0)" ::: "memory"); }
    if ((t & 1) == 0) SBAR;          // barrier every 2nd tile (single change vs R15)
    if (t + 2 < NT) STAGE16(t + 2, (t + 2) & 3)

    const unsigned short* Asc = LDSU + (t & 3) * 8192;
    const unsigned short* Bsc = LDSU + 32768 + (t & 3) * 8192;
    short8v Bf[4], Af[4];
#pragma unroll
    for (int j = 0; j < 4; ++j)
      Bf[j] = *(const short8v*)&Bsc[bbase + j * 512 + rdsw];
#pragma unroll
    for (int i = 0; i < 4; ++i)
      Af[i] = *(const short8v*)&Asc[abase + i * 512 + rdsw];

    __builtin_amdgcn_s_setprio(1);
#pragma unroll
    for (int i = 0; i < 4; ++i)
#pragma unroll
      for (int j = 0; j < 4; ++j)
        acc[i][j] = MFMA_BF16(Af[i], Bf[j], acc[i][j], 0, 0, 0);
    __builtin_amdgcn_s_setprio(0);
  }
#undef STAGE16
  SBAR;

  const int row0 = bm * 256 + wr * 64;
  const int col0 = bn * 256 + wcn * 64;
  unsigned short* sc = LDSU;

  const int seg = bn >> 2;             // 0=Q, 1=K, 2=V
  const int b = bm >> 3;               // batch
  float bvj[4];
#pragma unroll
  for (int j = 0; j < 4; ++j) bvj[j] = bias[col0 + j * 16 + l15];
  const int colL0 = col0 & 1023;
  if (seg < 2) {
#pragma unroll
    for (int i = 0; i < 4; ++i)
#pragma unroll
      for (int j = 0; j < 4; ++j) {
        const int p = wcn * 64 + j * 16 + l15;
        const int m = wr * 64 + i * 16 + lk * 4;
        us4 o;
#pragma unroll
        for (int r = 0; r < 4; ++r) o[r] = f2b(acc[i][j][r] + bvj[j]);
        *(us4*)&sc[p * 256 + (((m >> 3) ^ (p & 15)) << 3) + (m & 7)] = o;
      }
#pragma unroll
    for (int j = 0; j < 4; ++j) {
      const int colL = colL0 + j * 16 + l15;
      float ss = 0.f, sm = 0.f;
#pragma unroll
      for (int i = 0; i < 4; ++i)
#pragma unroll
        for (int r = 0; r < 4; ++r) {
          const float v = acc[i][j][r] + bvj[j];
          ss += v * v; sm += v;
        }
      ss = red4lk(ss);
      if (seg == 0) sm = red4lk(sm);
      if (lk == 0) {
        atomicAdd(&(seg == 0 ? r1 : r3)[(long)b * 1024 + colL], ss);
        if (seg == 0) atomicAdd(&r2[(long)b * 1024 + colL], sm);
      }
    }
    SBAR;
    unsigned short* tp = (seg == 0 ? (unsigned short*)O0 : (unsigned short*)O1)
                         + (long)b * 2097152;
    const int P0 = (bn & 3) * 256;
    const int M0 = (bm & 7) * 256;
#pragma unroll
    for (int it = 0; it < 8; ++it) {
      const int p = it * 32 + (tid >> 5);
      const int c = lane & 31;
      us8 v = *(const us8*)&sc[p * 256 + ((c ^ (p & 15)) << 3)];
      *(us8*)&tp[(long)(P0 + p) * 2048 + M0 + c * 8] = v;
    }
  } else {
#pragma unroll
    for (int i = 0; i < 4; ++i)
#pragma unroll
      for (int r = 0; r < 4; ++r) {
        const int rl = wr * 64 + i * 16 + lk * 4 + r;
        float sm = 0.f;
#pragma unroll
        for (int j = 0; j < 4; ++j) {
          const float v = acc[i][j][r] + bvj[j];
          sm += v;
          const int col = wcn * 64 + j * 16 + l15;
          sc[rl * 256 + (((col >> 3) ^ (rl & 15)) << 3) + (col & 7)] = f2b(v);
        }
        sm = red16(sm);
        if (l15 == 0) atomicAdd(&r4[row0 + i * 16 + lk * 4 + r], sm);
      }
    SBAR;
    unsigned short* outp = (unsigned short*)O2;
    const int C0 = (bn & 3) * 256;
#pragma unroll
    for (int it = 0; it < 8; ++it) {
      const int rl = it * 32 + (tid >> 5);
      const int c = lane & 31;
      us8 v = *(const us8*)&sc[rl * 256 + ((c ^ (rl & 15)) << 3)];
      *(us8*)&outp[(long)(bm * 256 + rl) * 1024 + C0 + c * 8] = v;
    }
  }
}

extern "C" void kernel_launch(void* const* d_in, const int* in_sizes, int n_in,
                              void* d_out, int out_size, void* d_ws, size_t ws_size,
                              hipStream_t stream) {
  (void)in_sizes; (void)n_in; (void)out_size;
  const float* x     = (const float*)d_in[0];
  const float* Wq    = (const float*)d_in[1];
  const float* bq    = (const float*)d_in[2];
  const float* Wk    = (const float*)d_in[3];
  const float* bk    = (const float*)d_in[4];
  const float* Wv    = (const float*)d_in[5];
  const float* bv    = (const float*)d_in[6];
  const float* gamma = (const float*)d_in[7];

  // B=16, C=2048, L=D=1024
  const long NE = 16L * 2048 * 1024;
  const long BUF = NE * 2;                    // bytes per bf16 tensor

  char* w = (char*)d_ws;
  unsigned short* QT  = (unsigned short*)(w);            // [16][1024][2048] bf16
  unsigned short* KT  = (unsigned short*)(w + BUF);      // [16][1024][2048] bf16
  unsigned short* Vh  = (unsigned short*)(w + 2 * BUF);  // [32768][1024]
  unsigned short* xh  = (unsigned short*)(w + 3 * BUF);  // live to the end
  unsigned short* S   = (unsigned short*)(w + 4 * BUF);  // [16][1024][1024] (33.5 MB)
  size_t off = 4 * (size_t)BUF + (size_t)BUF / 2 + 4096;
  unsigned short* Wqkvh = (unsigned short*)(w + off); off += 3 * 2097152;  // Wq|Wk|Wv
  char* accbase = w + off;
  float* pq     = (float*)(w + off); off += 65536;       // col sumsq of Q  (16x1024)
  float* qsum   = (float*)(w + off); off += 65536;       // col sum of Q
  float* pk     = (float*)(w + off); off += 65536;       // col sumsq of K
  float* Vsum   = (float*)(w + off); off += 131072;      // row sum of V    (16x2048)
  float* Srow   = (float*)(w + off); off += 65536;       // row sum of scaled S (16x1024)
  const size_t accbytes = (size_t)(w + off - accbase);
  float* invq   = (float*)(w + off); off += 65536;
  float* invk   = (float*)(w + off); off += 65536;
  float* tailor = (float*)(w + off); off += 65536;
  float* bqkv   = (float*)(w + off); off += 12288;
  if (ws_size < off) return;

  // 0) zero atomic accumulators
  hipMemsetAsync(accbase, 0, accbytes, stream);

  // 1) casts + bias concat
  k_f32_to_bf16<<<dim3((unsigned)(NE / 1024)), 256, 0, stream>>>(x, xh, NE);
  k_wcast<<<dim3(3072), 256, 0, stream>>>(Wq, Wk, Wv, Wqkvh);
  k_bias_cat<<<dim3(12), 256, 0, stream>>>(bq, bk, bv, bqkv);

  // 2) merged QKV GEMM (16-wave): M=32768, N=3072, K=1024; Q,K transposed + reductions
  k_g16qkv<<<dim3(12, 128, 1), 1024, 0, stream>>>(
      xh, Wqkvh, QT, KT, Vh, 1024, bqkv, pq, qsum, pk, Vsum);

  // 3) inverse norms
  k_norms_fin<<<dim3(64), 256, 0, stream>>>(pq, pk, invq, invk);

  // 4) S = invq.(QT x KT^T).invk per batch (8-wave; M=N=1024, K=2048) + scaled row sums
  k_g8<4><<<dim3(4, 4, 16), 512, 0, stream>>>(
      QT, KT, S, 2048, 1024L * 2048, 1024L * 2048, 1024L * 1024,
      Srow, invq, invk, nullptr, nullptr, nullptr, nullptr);

  // 5) tailor
  k_tailor_fin<<<dim3(64), 256, 0, stream>>>(Srow, invq, qsum, tailor);

  // 6) out = xh + gamma*(Vsum + V x S^T) * tailor   (8-wave; M=2048/batch, N=1024, K=1024)
  k_g8<1><<<dim3(4, 8, 16), 512, 0, stream>>>(
      Vh, S, d_out, 1024, 2048L * 1024, 1024L * 1024, 2048L * 1024,
      nullptr, nullptr, nullptr, xh, Vsum, tailor, gamma);
}

// Round 17
// 378.514 us; speedup vs baseline: 2.3124x; 1.2229x over previous
//
#include <hip/hip_runtime.h>
#include <cstdint>

#define DEV static __device__ __forceinline__

typedef __attribute__((ext_vector_type(8))) short short8v;     // 8 x bf16 bits
typedef __attribute__((ext_vector_type(4))) float f32x4;
typedef __attribute__((ext_vector_type(4))) float fl4;
typedef __attribute__((ext_vector_type(4))) unsigned short us4;
typedef __attribute__((ext_vector_type(8))) unsigned short us8;
typedef __attribute__((ext_vector_type(2))) long l2v;          // 2 x i64 (one b128)

DEV float b2f(unsigned short u) {
  union { unsigned int i; float f; } c; c.i = ((unsigned int)u) << 16; return c.f;
}
DEV unsigned short f2b(float f) {   // RNE float -> bf16 bits
  union { float f; unsigned int i; } c; c.f = f;
  unsigned int u = c.i;
  u += 0x7fffu + ((u >> 16) & 1u);
  return (unsigned short)(u >> 16);
}
DEV unsigned int f4_to_fp8x4(float a, float b, float c, float d) {  // 4 x e4m3 packed
  int r = __builtin_amdgcn_cvt_pk_fp8_f32(a, b, 0, false);
  r = __builtin_amdgcn_cvt_pk_fp8_f32(c, d, r, true);
  return (unsigned int)r;
}

DEV void gload16(const void* g, void* l) {  // async global->LDS, 16B/lane
  __builtin_amdgcn_global_load_lds(
      (const __attribute__((address_space(1))) unsigned int*)g,
      (__attribute__((address_space(3))) unsigned int*)l, 16, 0, 0);
}

DEV float red16(float v) {  // reduce across 16 lanes sharing lk (xor low 4 bits)
  v += __shfl_xor(v, 1); v += __shfl_xor(v, 2);
  v += __shfl_xor(v, 4); v += __shfl_xor(v, 8);
  return v;
}
DEV float red4lk(float v) { // reduce across the 4 lk groups (xor bits 4,5)
  v += __shfl_xor(v, 16); v += __shfl_xor(v, 32);
  return v;
}

// ---------------- x -> bf16 (residual) + fp8 (GEMM A operand) ----------------
__global__ __launch_bounds__(256) void k_xcast(const float* __restrict__ src,
                                               unsigned short* __restrict__ dh,
                                               unsigned char* __restrict__ d8, long n) {
  long i = ((long)blockIdx.x * 256 + threadIdx.x) * 4;
  if (i >= n) return;
  fl4 v = *(const fl4*)(src + i);
  us4 o;
  o[0] = f2b(v[0]); o[1] = f2b(v[1]); o[2] = f2b(v[2]); o[3] = f2b(v[3]);
  *(us4*)(dh + i) = o;
  *(unsigned int*)(d8 + i) = f4_to_fp8x4(v[0], v[1], v[2], v[3]);
}

// ---------------- Wq|Wk|Wv -> one contiguous fp8 buffer ----------------
__global__ __launch_bounds__(256) void k_wcast8(const float* __restrict__ wq,
                                                const float* __restrict__ wk,
                                                const float* __restrict__ wv,
                                                unsigned char* __restrict__ dst) {
  const long i = ((long)blockIdx.x * 256 + threadIdx.x) * 4;   // [0, 3M)
  const int seg = (int)(i >> 20);
  const float* s = seg == 0 ? wq : (seg == 1 ? wk : wv);
  fl4 v = *(const fl4*)(s + (i & 1048575));
  *(unsigned int*)(dst + i) = f4_to_fp8x4(v[0], v[1], v[2], v[3]);
}

// ---------------- concat biases into 3072-float buffer ----------------
__global__ __launch_bounds__(256) void k_bias_cat(const float* __restrict__ bq,
                                                  const float* __restrict__ bk,
                                                  const float* __restrict__ bv,
                                                  float* __restrict__ o) {
  const int t = blockIdx.x * 256 + threadIdx.x;   // 3072
  o[t] = t < 1024 ? bq[t] : (t < 2048 ? bk[t - 1024] : bv[t - 2048]);
}

// ---------------- finalize inverse norms ----------------
__global__ __launch_bounds__(256) void k_norms_fin(const float* __restrict__ pq,
                                                   const float* __restrict__ pk,
                                                   float* __restrict__ invq, float* __restrict__ invk) {
  const int gid = blockIdx.x * 256 + threadIdx.x;   // 16384
  invq[gid] = rsqrtf(pq[gid]);
  invk[gid] = rsqrtf(pk[gid]);
}

// ---------------- finalize tailor ----------------
__global__ __launch_bounds__(256) void k_tailor_fin(const float* __restrict__ Srow,
                                                    const float* __restrict__ invq,
                                                    const float* __restrict__ qsum,
                                                    float* __restrict__ tailor) {
  const int gid = blockIdx.x * 256 + threadIdx.x;   // 16384
  tailor[gid] = 1.0f / (1024.0f + Srow[gid] + 1e-6f * invq[gid] * qsum[gid]);
}

#define MFMA_BF16 __builtin_amdgcn_mfma_f32_16x16x32_bf16
#define MFMA_FP8(A, B, C) __builtin_amdgcn_mfma_f32_16x16x32_fp8_fp8((A), (B), (C), 0, 0, 0)
#define SBAR   __builtin_amdgcn_s_barrier()

// ================= 16-WAVE fp8 QKV =====================================================
// 256x256 NT GEMM, BK=64 fp8 (byte-geometry identical to verified bf16 BK=32: 64B rows,
// 4x16B chunks, same chunk swizzle, same staging formulas). Each b128 read = 2 i64
// fragments = 2 MFMA k-steps; A/B use the SAME k-permutation (self-consistent).
// Free-run: 4 LDS buffers, stage t+2, counted vmcnt(2), barrier every 2nd tile.
// Q/K stored TRANSPOSED as fp8 via LDS roundtrip + fused col reductions; V bf16 + row sums.
__global__ __launch_bounds__(1024, 4)
void k_g16qkv8(const unsigned char* __restrict__ A,
               const unsigned char* __restrict__ Bt,
               unsigned char* __restrict__ QT8, unsigned char* __restrict__ KT8,
               unsigned short* __restrict__ Vout,
               int Kb,
               const float* __restrict__ bias,
               float* __restrict__ r1, float* __restrict__ r2,
               float* __restrict__ r3, float* __restrict__ r4) {
  __shared__ __align__(16) unsigned char LDSU[131072];  // 4x16KB A | 4x16KB B; then scratch

  const int tid = threadIdx.x;
  const int wv = tid >> 6, lane = tid & 63;
  const int wr = wv >> 2, wcn = wv & 3;          // 4 x 4 wave grid, 64x64 each
  const int l15 = lane & 15, lk = lane >> 4;

  const int nx = gridDim.x;
  const int nwg = nx * gridDim.y;
  const int lin = blockIdx.y * nx + blockIdx.x;
  const int cpx = nwg >> 3;
  const int wg = (lin & 7) * cpx + (lin >> 3);
  const int bn = wg % nx;
  const int bm = wg / nx;

  const unsigned char* Ab = A + (long)bm * 256 * Kb;
  const unsigned char* Bb = Bt + (long)bn * 256 * Kb;

  // staging: row = tid>>2 (64B/row, 4 thr), phys chunk tid&3, pre-swz global chunk.
  const int scsw = (tid & 3) ^ ((tid >> 3) & 3);
  const long gOff = (long)(tid >> 2) * Kb + (long)scsw * 16;   // bytes; + t*64
  const int ldsb = wv * 1024;                                   // bytes

  const int rdsw = (lk ^ ((l15 >> 1) & 3)) * 16;                // bytes
  const int abase = (wr * 64 + l15) * 64;    // + i*1024
  const int bbase = (wcn * 64 + l15) * 64;   // + j*1024

  f32x4 acc[4][4];
#pragma unroll
  for (int i = 0; i < 4; ++i)
#pragma unroll
    for (int j = 0; j < 4; ++j) acc[i][j] = (f32x4){0.f, 0.f, 0.f, 0.f};

#define STAGEQ(T, BUF)                                                        \
  {                                                                           \
    const long kb = (long)(T) * 64;                                           \
    gload16(Ab + kb + gOff, LDSU + (BUF) * 16384 + ldsb);                     \
    gload16(Bb + kb + gOff, LDSU + 65536 + (BUF) * 16384 + ldsb);             \
  }

  STAGEQ(0, 0)
  STAGEQ(1, 1)

  const int NT = Kb >> 6;   // 16
  for (int t = 0; t < NT; ++t) {
    if (t < NT - 1) { asm volatile("s_waitcnt vmcnt(2)" ::: "memory"); }
    else            { asm volatile("s_waitcnt vmcnt(0)" ::: "memory"); }
    if ((t & 1) == 0) SBAR;
    if (t + 2 < NT) STAGEQ(t + 2, (t + 2) & 3)

    const unsigned char* Asc = LDSU + (t & 3) * 16384;
    const unsigned char* Bsc = LDSU + 65536 + (t & 3) * 16384;
    l2v Bf[4], Af[4];
#pragma unroll
    for (int j = 0; j < 4; ++j)
      Bf[j] = *(const l2v*)&Bsc[bbase + j * 1024 + rdsw];
#pragma unroll
    for (int i = 0; i < 4; ++i)
      Af[i] = *(const l2v*)&Asc[abase + i * 1024 + rdsw];

    __builtin_amdgcn_s_setprio(1);
#pragma unroll
    for (int i = 0; i < 4; ++i)
#pragma unroll
      for (int j = 0; j < 4; ++j) {
        acc[i][j] = MFMA_FP8(Af[i][0], Bf[j][0], acc[i][j]);
        acc[i][j] = MFMA_FP8(Af[i][1], Bf[j][1], acc[i][j]);
      }
    __builtin_amdgcn_s_setprio(0);
  }
#undef STAGEQ
  SBAR;   // K-loop LDS dead -> scratch

  const int row0 = bm * 256 + wr * 64;
  const int col0 = bn * 256 + wcn * 64;

  const int seg = bn >> 2;             // 0=Q, 1=K, 2=V
  const int b = bm >> 3;               // batch
  float bvj[4];
#pragma unroll
  for (int j = 0; j < 4; ++j) bvj[j] = bias[col0 + j * 16 + l15];
  const int colL0 = col0 & 1023;

  if (seg < 2) {
    // ---- transposed fp8 store: scratch [256 p][256 B], 16B cells, cell ^= p&15
    unsigned char* sc8 = LDSU;
#pragma unroll
    for (int i = 0; i < 4; ++i)
#pragma unroll
      for (int j = 0; j < 4; ++j) {
        const int p = wcn * 64 + j * 16 + l15;
        const int m = wr * 64 + i * 16 + lk * 4;     // aligned 4
        const unsigned int pk4 = f4_to_fp8x4(acc[i][j][0] + bvj[j], acc[i][j][1] + bvj[j],
                                             acc[i][j][2] + bvj[j], acc[i][j][3] + bvj[j]);
        *(unsigned int*)&sc8[p * 256 + (((m >> 4) ^ (p & 15)) << 4) + (m & 15)] = pk4;
      }
    // col reductions (exact fp32 values, pre-rounding)
#pragma unroll
    for (int j = 0; j < 4; ++j) {
      const int colL = colL0 + j * 16 + l15;
      float ss = 0.f, sm = 0.f;
#pragma unroll
      for (int i = 0; i < 4; ++i)
#pragma unroll
        for (int r = 0; r < 4; ++r) {
          const float v = acc[i][j][r] + bvj[j];
          ss += v * v; sm += v;
        }
      ss = red4lk(ss);
      if (seg == 0) sm = red4lk(sm);
      if (lk == 0) {
        atomicAdd(&(seg == 0 ? r1 : r3)[(long)b * 1024 + colL], ss);
        if (seg == 0) atomicAdd(&r2[(long)b * 1024 + colL], sm);
      }
    }
    SBAR;
    unsigned char* tp = (seg == 0 ? QT8 : KT8) + (long)b * 2097152;  // 1024*2048 B/batch
    const int P0 = (bn & 3) * 256;
    const int M0 = (bm & 7) * 256;
#pragma unroll
    for (int it = 0; it < 4; ++it) {
      const int p = it * 64 + (tid >> 4);            // [0,256)
      const int c = tid & 15;
      us8 v = *(const us8*)&sc8[p * 256 + ((c ^ (p & 15)) << 4)];
      *(us8*)&tp[(long)(P0 + p) * 2048 + M0 + c * 16] = v;
    }
  } else {
    // ---- V: bf16 normal layout + row sums (R16-verbatim)
    unsigned short* sc = (unsigned short*)LDSU;
#pragma unroll
    for (int i = 0; i < 4; ++i)
#pragma unroll
      for (int r = 0; r < 4; ++r) {
        const int rl = wr * 64 + i * 16 + lk * 4 + r;
        float sm = 0.f;
#pragma unroll
        for (int j = 0; j < 4; ++j) {
          const float v = acc[i][j][r] + bvj[j];
          sm += v;
          const int col = wcn * 64 + j * 16 + l15;
          sc[rl * 256 + (((col >> 3) ^ (rl & 15)) << 3) + (col & 7)] = f2b(v);
        }
        sm = red16(sm);
        if (l15 == 0) atomicAdd(&r4[row0 + i * 16 + lk * 4 + r], sm);
      }
    SBAR;
    const int C0 = (bn & 3) * 256;
#pragma unroll
    for (int it = 0; it < 8; ++it) {
      const int rl = it * 32 + (tid >> 5);
      const int c = lane & 31;
      us8 v = *(const us8*)&sc[rl * 256 + ((c ^ (rl & 15)) << 3)];
      *(us8*)&Vout[(long)(bm * 256 + rl) * 1024 + C0 + c * 8] = v;
    }
  }
}

// ================= 8-WAVE fp8 S-GEMM ===================================================
// 256x256 NT, BK=64 fp8, 8 waves (2Mx4N, 128x64 each). Free-run: 4 buffers, stage t+2,
// vmcnt(4), barrier every 2nd tile. Epilogue: S = invq[p]*invk[l]*acc -> bf16 + row sums.
__global__ __launch_bounds__(512)
void k_g8s8(const unsigned char* __restrict__ A,
            const unsigned char* __restrict__ Bt,
            unsigned short* __restrict__ Sout,
            int Kb, long sA, long sB, long sC,
            float* __restrict__ Srow, const float* __restrict__ invq,
            const float* __restrict__ invk) {
  __shared__ __align__(16) unsigned char LDSU[131072];

  const int tid = threadIdx.x;
  const int wv = tid >> 6, lane = tid & 63;
  const int wr = wv >> 2, wcn = wv & 3;
  const int l15 = lane & 15, lk = lane >> 4;

  const int nx = gridDim.x;
  const int nwg = nx * gridDim.y;
  const int lin = blockIdx.y * nx + blockIdx.x;
  const int cpx = nwg >> 3;
  const int wg = (lin & 7) * cpx + (lin >> 3);
  const int bn = wg % nx;
  const int bm = wg / nx;
  const int bz = blockIdx.z;

  const unsigned char* Ab = A + (long)bz * sA + (long)bm * 256 * Kb;
  const unsigned char* Bb = Bt + (long)bz * sB + (long)bn * 256 * Kb;

  const int scsw = (tid & 3) ^ ((tid >> 3) & 3);
  const long gOff = (long)(tid >> 2) * Kb + (long)scsw * 16;   // + q*128*Kb + t*64
  const int ldsb = wv * 1024;                                   // + q*8192

  const int rdsw = (lk ^ ((l15 >> 1) & 3)) * 16;
  const int abase = (wr * 128 + l15) * 64;   // + i*1024
  const int bbase = (wcn * 64 + l15) * 64;   // + j*1024

  f32x4 acc[8][4];
#pragma unroll
  for (int i = 0; i < 8; ++i)
#pragma unroll
    for (int j = 0; j < 4; ++j) acc[i][j] = (f32x4){0.f, 0.f, 0.f, 0.f};

#define STAGES(T, BUF)                                                        \
  {                                                                           \
    const long kb = (long)(T) * 64;                                           \
    unsigned char* Asb = LDSU + (BUF) * 16384;                                \
    unsigned char* Bsb = LDSU + 65536 + (BUF) * 16384;                        \
    gload16(Ab + kb + gOff,              &Asb[ldsb]);                         \
    gload16(Ab + kb + gOff + 128L * Kb,  &Asb[8192 + ldsb]);                  \
    gload16(Bb + kb + gOff,              &Bsb[ldsb]);                         \
    gload16(Bb + kb + gOff + 128L * Kb,  &Bsb[8192 + ldsb]);                  \
  }

  STAGES(0, 0)
  STAGES(1, 1)

  const int NT = Kb >> 6;
  for (int t = 0; t < NT; ++t) {
    if (t < NT - 1) { asm volatile("s_waitcnt vmcnt(4)" ::: "memory"); }
    else            { asm volatile("s_waitcnt vmcnt(0)" ::: "memory"); }
    if ((t & 1) == 0) SBAR;
    if (t + 2 < NT) STAGES(t + 2, (t + 2) & 3)

    const unsigned char* Asc = LDSU + (t & 3) * 16384;
    const unsigned char* Bsc = LDSU + 65536 + (t & 3) * 16384;
    l2v Bf[4], Af[8];
#pragma unroll
    for (int j = 0; j < 4; ++j)
      Bf[j] = *(const l2v*)&Bsc[bbase + j * 1024 + rdsw];
#pragma unroll
    for (int i = 0; i < 8; ++i)
      Af[i] = *(const l2v*)&Asc[abase + i * 1024 + rdsw];

    __builtin_amdgcn_s_setprio(1);
#pragma unroll
    for (int i = 0; i < 8; ++i)
#pragma unroll
      for (int j = 0; j < 4; ++j) {
        acc[i][j] = MFMA_FP8(Af[i][0], Bf[j][0], acc[i][j]);
        acc[i][j] = MFMA_FP8(Af[i][1], Bf[j][1], acc[i][j]);
      }
    __builtin_amdgcn_s_setprio(0);
  }
#undef STAGES
  SBAR;

  const int row0 = bm * 256 + wr * 128;
  const int col0 = bn * 256 + wcn * 64;
  unsigned short* sc = (unsigned short*)LDSU;

  float ivk[4];
#pragma unroll
  for (int j = 0; j < 4; ++j) ivk[j] = invk[bz * 1024 + col0 + j * 16 + l15];
#pragma unroll
  for (int i = 0; i < 8; ++i) {
    float ivq[4];
#pragma unroll
    for (int r = 0; r < 4; ++r) ivq[r] = invq[bz * 1024 + row0 + i * 16 + lk * 4 + r];
#pragma unroll
    for (int r = 0; r < 4; ++r) {
      const int rl = wr * 128 + i * 16 + lk * 4 + r;
      float sm = 0.f;
#pragma unroll
      for (int j = 0; j < 4; ++j) {
        const float v = acc[i][j][r] * ivq[r] * ivk[j];
        sm += v;
        const int col = wcn * 64 + j * 16 + l15;
        sc[rl * 256 + (((col >> 3) ^ (rl & 15)) << 3) + (col & 7)] = f2b(v);
      }
      sm = red16(sm);
      if (l15 == 0) atomicAdd(&Srow[(long)bz * 1024 + row0 + i * 16 + lk * 4 + r], sm);
    }
  }
  SBAR;
  unsigned short* Cb = Sout + (long)bz * sC;
#pragma unroll
  for (int it = 0; it < 16; ++it) {
    const int rl = it * 16 + wv * 2 + (lane >> 5);
    const int c = lane & 31;
    us8 v = *(const us8*)&sc[rl * 256 + ((c ^ (rl & 15)) << 3)];
    *(us8*)&Cb[(long)(bm * 256 + rl) * 1024 + bn * 256 + c * 8] = v;
  }
}

// ================= 8-WAVE bf16 final GEMM (R16-verbatim, EPI 1 only) ===================
__global__ __launch_bounds__(512)
void k_g8fin(const unsigned short* __restrict__ A,
             const unsigned short* __restrict__ Bt,
             float* __restrict__ O0,
             int K, long sA, long sB, long sC,
             const unsigned short* __restrict__ xh,
             const float* __restrict__ Vsum,
             const float* __restrict__ tailor,
             const float* __restrict__ gptr) {
  __shared__ __align__(16) unsigned short LDSU[65536];

  const int tid = threadIdx.x;
  const int wv = tid >> 6, lane = tid & 63;
  const int wr = wv >> 2, wcn = wv & 3;
  const int l15 = lane & 15, lk = lane >> 4;

  const int nx = gridDim.x;
  const int nwg = nx * gridDim.y;
  const int lin = blockIdx.y * nx + blockIdx.x;
  const int cpx = nwg >> 3;
  const int wg = (lin & 7) * cpx + (lin >> 3);
  const int bn = wg % nx;
  const int bm = wg / nx;
  const int bz = blockIdx.z;

  const unsigned short* Ab = A + (long)bz * sA + (long)bm * 256 * K;
  const unsigned short* Bb = Bt + (long)bz * sB + (long)bn * 256 * K;

  const int scsw = (tid & 3) ^ ((tid >> 3) & 3);
  const long gOff = (long)(tid >> 2) * K + (long)scsw * 8;
  const int ldsb = wv * 512;

  const int rdsw = (lk ^ ((l15 >> 1) & 3)) * 8;
  const int abase = (wr * 128 + l15) * 32;
  const int bbase = (wcn * 64 + l15) * 32;

  f32x4 acc[8][4];
#pragma unroll
  for (int i = 0; i < 8; ++i)
#pragma unroll
    for (int j = 0; j < 4; ++j) acc[i][j] = (f32x4){0.f, 0.f, 0.f, 0.f};

#define STAGE8(T, BUF)                                                       \
  {                                                                          \
    const long kb = (long)(T) * 32;                                          \
    unsigned short* Asb = LDSU + (BUF) * 8192;                               \
    unsigned short* Bsb = LDSU + 32768 + (BUF) * 8192;                       \
    gload16(Ab + kb + gOff,            &Asb[ldsb]);                          \
    gload16(Ab + kb + gOff + 128L * K, &Asb[4096 + ldsb]);                   \
    gload16(Bb + kb + gOff,            &Bsb[ldsb]);                          \
    gload16(Bb + kb + gOff + 128L * K, &Bsb[4096 + ldsb]);                   \
  }

  STAGE8(0, 0)
  STAGE8(1, 1)

  const int NT = K >> 5;
  for (int t = 0; t < NT; ++t) {
    if (t < NT - 1) { asm volatile("s_waitcnt vmcnt(4)" ::: "memory"); }
    else            { asm volatile("s_waitcnt vmcnt(0)" ::: "memory"); }
    if ((t & 1) == 0) SBAR;
    if (t + 2 < NT) STAGE8(t + 2, (t + 2) & 3)

    const unsigned short* Asc = LDSU + (t & 3) * 8192;
    const unsigned short* Bsc = LDSU + 32768 + (t & 3) * 8192;
    short8v Bf[4], Af[8];
#pragma unroll
    for (int j = 0; j < 4; ++j)
      Bf[j] = *(const short8v*)&Bsc[bbase + j * 512 + rdsw];
#pragma unroll
    for (int i = 0; i < 8; ++i)
      Af[i] = *(const short8v*)&Asc[abase + i * 512 + rdsw];

    __builtin_amdgcn_s_setprio(1);
#pragma unroll
    for (int i = 0; i < 8; ++i)
#pragma unroll
      for (int j = 0; j < 4; ++j)
        acc[i][j] = MFMA_BF16(Af[i], Bf[j], acc[i][j], 0, 0, 0);
    __builtin_amdgcn_s_setprio(0);
  }
#undef STAGE8
  SBAR;

  float* scf = (float*)LDSU;
  float* Cb = O0 + (long)bz * sC;
  const float g = gptr[0];
#pragma unroll
  for (int h = 0; h < 2; ++h) {
    if (wr == h) {
#pragma unroll
      for (int i = 0; i < 8; ++i)
#pragma unroll
        for (int j = 0; j < 4; ++j) {
          const int col = wcn * 64 + j * 16 + l15;
          const int cc = col >> 2, c3 = col & 3;
#pragma unroll
          for (int r = 0; r < 4; ++r) {
            const int rl = i * 16 + lk * 4 + r;
            scf[rl * 256 + ((cc ^ (rl & 15)) << 2) + c3] = acc[i][j][r];
          }
        }
    }
    SBAR;
#pragma unroll
    for (int it = 0; it < 16; ++it) {
      const int rl = it * 8 + wv;
      const int rg = bm * 256 + h * 128 + rl;
      const int c = lane;
      fl4 a4 = *(const fl4*)&scf[rl * 256 + ((c ^ (rl & 15)) << 2)];
      const int cg = bn * 256 + c * 4;
      us4 xv = *(const us4*)&xh[((long)bz * 2048 + rg) * 1024 + cg];
      fl4 tl = *(const fl4*)&tailor[bz * 1024 + cg];
      const float vs = Vsum[bz * 2048 + rg];
      fl4 o;
#pragma unroll
      for (int q = 0; q < 4; ++q) o[q] = b2f(xv[q]) + g * ((vs + a4[q]) * tl[q]);
      *(fl4*)&Cb[(long)rg * 1024 + cg] = o;
    }
    if (h == 0) SBAR;
  }
}

extern "C" void kernel_launch(void* const* d_in, const int* in_sizes, int n_in,
                              void* d_out, int out_size, void* d_ws, size_t ws_size,
                              hipStream_t stream) {
  (void)in_sizes; (void)n_in; (void)out_size;
  const float* x     = (const float*)d_in[0];
  const float* Wq    = (const float*)d_in[1];
  const float* bq    = (const float*)d_in[2];
  const float* Wk    = (const float*)d_in[3];
  const float* bk    = (const float*)d_in[4];
  const float* Wv    = (const float*)d_in[5];
  const float* bv    = (const float*)d_in[6];
  const float* gamma = (const float*)d_in[7];

  // B=16, C=2048, L=D=1024
  const long NE = 16L * 2048 * 1024;

  char* w = (char*)d_ws;
  unsigned char*  QT8 = (unsigned char*)(w);                    // [16][1024][2048] fp8
  unsigned char*  KT8 = (unsigned char*)(w + 33554432L);
  unsigned short* Vh  = (unsigned short*)(w + 67108864L);       // [32768][1024] bf16
  unsigned short* xh  = (unsigned short*)(w + 134217728L);      // bf16 residual
  unsigned char*  x8  = (unsigned char*)(w + 201326592L);       // [32768][1024] fp8
  unsigned short* S   = (unsigned short*)(w + 234881024L);      // [16][1024][1024] bf16
  size_t off = 268435456L;
  unsigned char* W8   = (unsigned char*)(w + off); off += 3145728;  // Wq|Wk|Wv fp8
  char* accbase = w + off;
  float* pq     = (float*)(w + off); off += 65536;
  float* qsum   = (float*)(w + off); off += 65536;
  float* pk     = (float*)(w + off); off += 65536;
  float* Vsum   = (float*)(w + off); off += 131072;
  float* Srow   = (float*)(w + off); off += 65536;
  const size_t accbytes = (size_t)(w + off - accbase);
  float* invq   = (float*)(w + off); off += 65536;
  float* invk   = (float*)(w + off); off += 65536;
  float* tailor = (float*)(w + off); off += 65536;
  float* bqkv   = (float*)(w + off); off += 12288;
  if (ws_size < off) return;

  // 0) zero atomic accumulators
  hipMemsetAsync(accbase, 0, accbytes, stream);

  // 1) casts + bias concat
  k_xcast<<<dim3((unsigned)(NE / 1024)), 256, 0, stream>>>(x, xh, x8, NE);
  k_wcast8<<<dim3(3072), 256, 0, stream>>>(Wq, Wk, Wv, W8);
  k_bias_cat<<<dim3(12), 256, 0, stream>>>(bq, bk, bv, bqkv);

  // 2) merged QKV GEMM (fp8, 16-wave): M=32768, N=3072, K=1024
  k_g16qkv8<<<dim3(12, 128, 1), 1024, 0, stream>>>(
      x8, W8, QT8, KT8, Vh, 1024, bqkv, pq, qsum, pk, Vsum);

  // 3) inverse norms
  k_norms_fin<<<dim3(64), 256, 0, stream>>>(pq, pk, invq, invk);

  // 4) S = invq.(QT8 x KT8^T).invk per batch (fp8, 8-wave; M=N=1024, K=2048)
  k_g8s8<<<dim3(4, 4, 16), 512, 0, stream>>>(
      QT8, KT8, S, 2048, 1024L * 2048, 1024L * 2048, 1024L * 1024,
      Srow, invq, invk);

  // 5) tailor
  k_tailor_fin<<<dim3(64), 256, 0, stream>>>(Srow, invq, qsum, tailor);

  // 6) out = xh + gamma*(Vsum + V x S^T) * tailor   (bf16, 8-wave)
  k_g8fin<<<dim3(4, 8, 16), 512, 0, stream>>>(
      Vh, S, (float*)d_out, 1024, 2048L * 1024, 1024L * 1024, 2048L * 1024,
      xh, Vsum, tailor, gamma);
}

// Round 18
// 350.411 us; speedup vs baseline: 2.4979x; 1.0802x over previous
//
#include <hip/hip_runtime.h>
#include <cstdint>

#define DEV static __device__ __forceinline__

typedef __attribute__((ext_vector_type(4))) float f32x4;
typedef __attribute__((ext_vector_type(4))) float fl4;
typedef __attribute__((ext_vector_type(4))) unsigned short us4;
typedef __attribute__((ext_vector_type(8))) unsigned short us8;
typedef __attribute__((ext_vector_type(2))) long l2v;          // 2 x i64 (one b128)

DEV float b2f(unsigned short u) {
  union { unsigned int i; float f; } c; c.i = ((unsigned int)u) << 16; return c.f;
}
DEV unsigned short f2b(float f) {   // RNE float -> bf16 bits
  union { float f; unsigned int i; } c; c.f = f;
  unsigned int u = c.i;
  u += 0x7fffu + ((u >> 16) & 1u);
  return (unsigned short)(u >> 16);
}
DEV unsigned int f4_to_fp8x4(float a, float b, float c, float d) {  // 4 x e4m3 packed
  int r = __builtin_amdgcn_cvt_pk_fp8_f32(a, b, 0, false);
  r = __builtin_amdgcn_cvt_pk_fp8_f32(c, d, r, true);
  return (unsigned int)r;
}
DEV unsigned char f2f8(float v) {   // scalar e4m3
  return (unsigned char)__builtin_amdgcn_cvt_pk_fp8_f32(v, v, 0, false);
}

DEV void gload16(const void* g, void* l) {  // async global->LDS, 16B/lane
  __builtin_amdgcn_global_load_lds(
      (const __attribute__((address_space(1))) unsigned int*)g,
      (__attribute__((address_space(3))) unsigned int*)l, 16, 0, 0);
}

DEV float red16(float v) {  // reduce across 16 lanes sharing lk (xor low 4 bits)
  v += __shfl_xor(v, 1); v += __shfl_xor(v, 2);
  v += __shfl_xor(v, 4); v += __shfl_xor(v, 8);
  return v;
}
DEV float red4lk(float v) { // reduce across the 4 lk groups (xor bits 4,5)
  v += __shfl_xor(v, 16); v += __shfl_xor(v, 32);
  return v;
}

// ---------------- x -> bf16 (residual) + fp8 (GEMM A operand) ----------------
__global__ __launch_bounds__(256) void k_xcast(const float* __restrict__ src,
                                               unsigned short* __restrict__ dh,
                                               unsigned char* __restrict__ d8, long n) {
  long i = ((long)blockIdx.x * 256 + threadIdx.x) * 4;
  if (i >= n) return;
  fl4 v = *(const fl4*)(src + i);
  us4 o;
  o[0] = f2b(v[0]); o[1] = f2b(v[1]); o[2] = f2b(v[2]); o[3] = f2b(v[3]);
  *(us4*)(dh + i) = o;
  *(unsigned int*)(d8 + i) = f4_to_fp8x4(v[0], v[1], v[2], v[3]);
}

// ---------------- Wq|Wk|Wv -> one contiguous fp8 buffer ----------------
__global__ __launch_bounds__(256) void k_wcast8(const float* __restrict__ wq,
                                                const float* __restrict__ wk,
                                                const float* __restrict__ wv,
                                                unsigned char* __restrict__ dst) {
  const long i = ((long)blockIdx.x * 256 + threadIdx.x) * 4;   // [0, 3M)
  const int seg = (int)(i >> 20);
  const float* s = seg == 0 ? wq : (seg == 1 ? wk : wv);
  fl4 v = *(const fl4*)(s + (i & 1048575));
  *(unsigned int*)(dst + i) = f4_to_fp8x4(v[0], v[1], v[2], v[3]);
}

// ---------------- concat biases into 3072-float buffer ----------------
__global__ __launch_bounds__(256) void k_bias_cat(const float* __restrict__ bq,
                                                  const float* __restrict__ bk,
                                                  const float* __restrict__ bv,
                                                  float* __restrict__ o) {
  const int t = blockIdx.x * 256 + threadIdx.x;   // 3072
  o[t] = t < 1024 ? bq[t] : (t < 2048 ? bk[t - 1024] : bv[t - 2048]);
}

// ---------------- finalize inverse norms ----------------
__global__ __launch_bounds__(256) void k_norms_fin(const float* __restrict__ pq,
                                                   const float* __restrict__ pk,
                                                   float* __restrict__ invq, float* __restrict__ invk) {
  const int gid = blockIdx.x * 256 + threadIdx.x;   // 16384
  invq[gid] = rsqrtf(pq[gid]);
  invk[gid] = rsqrtf(pk[gid]);
}

// ---------------- finalize tailor ----------------
__global__ __launch_bounds__(256) void k_tailor_fin(const float* __restrict__ Srow,
                                                    const float* __restrict__ invq,
                                                    const float* __restrict__ qsum,
                                                    float* __restrict__ tailor) {
  const int gid = blockIdx.x * 256 + threadIdx.x;   // 16384
  tailor[gid] = 1.0f / (1024.0f + Srow[gid] + 1e-6f * invq[gid] * qsum[gid]);
}

#define MFMA_FP8(A, B, C) __builtin_amdgcn_mfma_f32_16x16x32_fp8_fp8((A), (B), (C), 0, 0, 0)
#define SBAR   __builtin_amdgcn_s_barrier()

// ================= 16-WAVE fp8 QKV (R17-verbatim except V now stored fp8) ==============
__global__ __launch_bounds__(1024, 4)
void k_g16qkv8(const unsigned char* __restrict__ A,
               const unsigned char* __restrict__ Bt,
               unsigned char* __restrict__ QT8, unsigned char* __restrict__ KT8,
               unsigned char* __restrict__ Vout8,
               int Kb,
               const float* __restrict__ bias,
               float* __restrict__ r1, float* __restrict__ r2,
               float* __restrict__ r3, float* __restrict__ r4) {
  __shared__ __align__(16) unsigned char LDSU[131072];

  const int tid = threadIdx.x;
  const int wv = tid >> 6, lane = tid & 63;
  const int wr = wv >> 2, wcn = wv & 3;          // 4 x 4 wave grid, 64x64 each
  const int l15 = lane & 15, lk = lane >> 4;

  const int nx = gridDim.x;
  const int nwg = nx * gridDim.y;
  const int lin = blockIdx.y * nx + blockIdx.x;
  const int cpx = nwg >> 3;
  const int wg = (lin & 7) * cpx + (lin >> 3);
  const int bn = wg % nx;
  const int bm = wg / nx;

  const unsigned char* Ab = A + (long)bm * 256 * Kb;
  const unsigned char* Bb = Bt + (long)bn * 256 * Kb;

  const int scsw = (tid & 3) ^ ((tid >> 3) & 3);
  const long gOff = (long)(tid >> 2) * Kb + (long)scsw * 16;   // bytes; + t*64
  const int ldsb = wv * 1024;

  const int rdsw = (lk ^ ((l15 >> 1) & 3)) * 16;
  const int abase = (wr * 64 + l15) * 64;
  const int bbase = (wcn * 64 + l15) * 64;

  f32x4 acc[4][4];
#pragma unroll
  for (int i = 0; i < 4; ++i)
#pragma unroll
    for (int j = 0; j < 4; ++j) acc[i][j] = (f32x4){0.f, 0.f, 0.f, 0.f};

#define STAGEQ(T, BUF)                                                        \
  {                                                                           \
    const long kb = (long)(T) * 64;                                           \
    gload16(Ab + kb + gOff, LDSU + (BUF) * 16384 + ldsb);                     \
    gload16(Bb + kb + gOff, LDSU + 65536 + (BUF) * 16384 + ldsb);             \
  }

  STAGEQ(0, 0)
  STAGEQ(1, 1)

  const int NT = Kb >> 6;
  for (int t = 0; t < NT; ++t) {
    if (t < NT - 1) { asm volatile("s_waitcnt vmcnt(2)" ::: "memory"); }
    else            { asm volatile("s_waitcnt vmcnt(0)" ::: "memory"); }
    if ((t & 1) == 0) SBAR;
    if (t + 2 < NT) STAGEQ(t + 2, (t + 2) & 3)

    const unsigned char* Asc = LDSU + (t & 3) * 16384;
    const unsigned char* Bsc = LDSU + 65536 + (t & 3) * 16384;
    l2v Bf[4], Af[4];
#pragma unroll
    for (int j = 0; j < 4; ++j)
      Bf[j] = *(const l2v*)&Bsc[bbase + j * 1024 + rdsw];
#pragma unroll
    for (int i = 0; i < 4; ++i)
      Af[i] = *(const l2v*)&Asc[abase + i * 1024 + rdsw];

    __builtin_amdgcn_s_setprio(1);
#pragma unroll
    for (int i = 0; i < 4; ++i)
#pragma unroll
      for (int j = 0; j < 4; ++j) {
        acc[i][j] = MFMA_FP8(Af[i][0], Bf[j][0], acc[i][j]);
        acc[i][j] = MFMA_FP8(Af[i][1], Bf[j][1], acc[i][j]);
      }
    __builtin_amdgcn_s_setprio(0);
  }
#undef STAGEQ
  SBAR;   // K-loop LDS dead -> scratch

  const int row0 = bm * 256 + wr * 64;
  const int col0 = bn * 256 + wcn * 64;

  const int seg = bn >> 2;             // 0=Q, 1=K, 2=V
  const int b = bm >> 3;               // batch
  float bvj[4];
#pragma unroll
  for (int j = 0; j < 4; ++j) bvj[j] = bias[col0 + j * 16 + l15];
  const int colL0 = col0 & 1023;
  unsigned char* sc8 = LDSU;           // [256][256B] fp8 scratch, 16B cells ^ (row&15)

  if (seg < 2) {
    // transposed fp8 store (R17-verbatim)
#pragma unroll
    for (int i = 0; i < 4; ++i)
#pragma unroll
      for (int j = 0; j < 4; ++j) {
        const int p = wcn * 64 + j * 16 + l15;
        const int m = wr * 64 + i * 16 + lk * 4;
        const unsigned int pk4 = f4_to_fp8x4(acc[i][j][0] + bvj[j], acc[i][j][1] + bvj[j],
                                             acc[i][j][2] + bvj[j], acc[i][j][3] + bvj[j]);
        *(unsigned int*)&sc8[p * 256 + (((m >> 4) ^ (p & 15)) << 4) + (m & 15)] = pk4;
      }
#pragma unroll
    for (int j = 0; j < 4; ++j) {
      const int colL = colL0 + j * 16 + l15;
      float ss = 0.f, sm = 0.f;
#pragma unroll
      for (int i = 0; i < 4; ++i)
#pragma unroll
        for (int r = 0; r < 4; ++r) {
          const float v = acc[i][j][r] + bvj[j];
          ss += v * v; sm += v;
        }
      ss = red4lk(ss);
      if (seg == 0) sm = red4lk(sm);
      if (lk == 0) {
        atomicAdd(&(seg == 0 ? r1 : r3)[(long)b * 1024 + colL], ss);
        if (seg == 0) atomicAdd(&r2[(long)b * 1024 + colL], sm);
      }
    }
    SBAR;
    unsigned char* tp = (seg == 0 ? QT8 : KT8) + (long)b * 2097152;
    const int P0 = (bn & 3) * 256;
    const int M0 = (bm & 7) * 256;
#pragma unroll
    for (int it = 0; it < 4; ++it) {
      const int p = it * 64 + (tid >> 4);
      const int c = tid & 15;
      us8 v = *(const us8*)&sc8[p * 256 + ((c ^ (p & 15)) << 4)];
      *(us8*)&tp[(long)(P0 + p) * 2048 + M0 + c * 16] = v;
    }
  } else {
    // V: fp8 normal layout + fp32 row sums (byte stores to swizzled scratch)
#pragma unroll
    for (int i = 0; i < 4; ++i)
#pragma unroll
      for (int r = 0; r < 4; ++r) {
        const int rl = wr * 64 + i * 16 + lk * 4 + r;
        float sm = 0.f;
#pragma unroll
        for (int j = 0; j < 4; ++j) {
          const float v = acc[i][j][r] + bvj[j];
          sm += v;
          const int col = wcn * 64 + j * 16 + l15;
          sc8[rl * 256 + (((col >> 4) ^ (rl & 15)) << 4) + (col & 15)] = f2f8(v);
        }
        sm = red16(sm);
        if (l15 == 0) atomicAdd(&r4[row0 + i * 16 + lk * 4 + r], sm);
      }
    SBAR;
    const int C0 = (bn & 3) * 256;
#pragma unroll
    for (int it = 0; it < 4; ++it) {
      const int rl = it * 64 + (tid >> 4);
      const int c = tid & 15;
      us8 v = *(const us8*)&sc8[rl * 256 + ((c ^ (rl & 15)) << 4)];
      *(us8*)&Vout8[(long)(bm * 256 + rl) * 1024 + C0 + c * 16] = v;
    }
  }
}

// ================= 8-WAVE fp8 GEMM (S and final) ======================================
// 256x256 NT, BK=64 fp8, 8 waves (2Mx4N, 128x64 each). Free-run: 4 buffers, stage t+2,
// vmcnt(4), barrier every 2nd tile.
// EPI 4: S = invq[p]*invk[l]*acc -> fp8 out + fp32 row sums (r1=Srow, r2=invq, r3=invk).
// EPI 1: final fused fp32 epilogue (residual bf16 xh, Vsum, tailor, gamma).
template<int EPI>
__global__ __launch_bounds__(512)
void k_g8f8(const unsigned char* __restrict__ A,
            const unsigned char* __restrict__ Bt,
            void* __restrict__ O0,
            int Kb, long sA, long sB, long sC,
            float* __restrict__ r1, const float* __restrict__ r2,
            const float* __restrict__ r3,
            const unsigned short* __restrict__ xh,
            const float* __restrict__ Vsum,
            const float* __restrict__ tailor,
            const float* __restrict__ gptr) {
  __shared__ __align__(16) unsigned char LDSU[131072];

  const int tid = threadIdx.x;
  const int wv = tid >> 6, lane = tid & 63;
  const int wr = wv >> 2, wcn = wv & 3;
  const int l15 = lane & 15, lk = lane >> 4;

  const int nx = gridDim.x;
  const int nwg = nx * gridDim.y;
  const int lin = blockIdx.y * nx + blockIdx.x;
  const int cpx = nwg >> 3;
  const int wg = (lin & 7) * cpx + (lin >> 3);
  const int bn = wg % nx;
  const int bm = wg / nx;
  const int bz = blockIdx.z;

  const unsigned char* Ab = A + (long)bz * sA + (long)bm * 256 * Kb;
  const unsigned char* Bb = Bt + (long)bz * sB + (long)bn * 256 * Kb;

  const int scsw = (tid & 3) ^ ((tid >> 3) & 3);
  const long gOff = (long)(tid >> 2) * Kb + (long)scsw * 16;
  const int ldsb = wv * 1024;

  const int rdsw = (lk ^ ((l15 >> 1) & 3)) * 16;
  const int abase = (wr * 128 + l15) * 64;
  const int bbase = (wcn * 64 + l15) * 64;

  f32x4 acc[8][4];
#pragma unroll
  for (int i = 0; i < 8; ++i)
#pragma unroll
    for (int j = 0; j < 4; ++j) acc[i][j] = (f32x4){0.f, 0.f, 0.f, 0.f};

#define STAGES(T, BUF)                                                        \
  {                                                                           \
    const long kb = (long)(T) * 64;                                           \
    unsigned char* Asb = LDSU + (BUF) * 16384;                                \
    unsigned char* Bsb = LDSU + 65536 + (BUF) * 16384;                        \
    gload16(Ab + kb + gOff,              &Asb[ldsb]);                         \
    gload16(Ab + kb + gOff + 128L * Kb,  &Asb[8192 + ldsb]);                  \
    gload16(Bb + kb + gOff,              &Bsb[ldsb]);                         \
    gload16(Bb + kb + gOff + 128L * Kb,  &Bsb[8192 + ldsb]);                  \
  }

  STAGES(0, 0)
  STAGES(1, 1)

  const int NT = Kb >> 6;
  for (int t = 0; t < NT; ++t) {
    if (t < NT - 1) { asm volatile("s_waitcnt vmcnt(4)" ::: "memory"); }
    else            { asm volatile("s_waitcnt vmcnt(0)" ::: "memory"); }
    if ((t & 1) == 0) SBAR;
    if (t + 2 < NT) STAGES(t + 2, (t + 2) & 3)

    const unsigned char* Asc = LDSU + (t & 3) * 16384;
    const unsigned char* Bsc = LDSU + 65536 + (t & 3) * 16384;
    l2v Bf[4], Af[8];
#pragma unroll
    for (int j = 0; j < 4; ++j)
      Bf[j] = *(const l2v*)&Bsc[bbase + j * 1024 + rdsw];
#pragma unroll
    for (int i = 0; i < 8; ++i)
      Af[i] = *(const l2v*)&Asc[abase + i * 1024 + rdsw];

    __builtin_amdgcn_s_setprio(1);
#pragma unroll
    for (int i = 0; i < 8; ++i)
#pragma unroll
      for (int j = 0; j < 4; ++j) {
        acc[i][j] = MFMA_FP8(Af[i][0], Bf[j][0], acc[i][j]);
        acc[i][j] = MFMA_FP8(Af[i][1], Bf[j][1], acc[i][j]);
      }
    __builtin_amdgcn_s_setprio(0);
  }
#undef STAGES
  SBAR;

  const int row0 = bm * 256 + wr * 128;
  const int col0 = bn * 256 + wcn * 64;

  if constexpr (EPI == 4) {
    // S epilogue: scale, fp8 byte-store to swizzled scratch, fp32 row sums, 16B readback
    unsigned char* sc8 = LDSU;
    unsigned char* Cb = (unsigned char*)O0 + (long)bz * sC;
    float ivk[4];
#pragma unroll
    for (int j = 0; j < 4; ++j) ivk[j] = r3[bz * 1024 + col0 + j * 16 + l15];
#pragma unroll
    for (int i = 0; i < 8; ++i) {
      float ivq[4];
#pragma unroll
      for (int r = 0; r < 4; ++r) ivq[r] = r2[bz * 1024 + row0 + i * 16 + lk * 4 + r];
#pragma unroll
      for (int r = 0; r < 4; ++r) {
        const int rl = wr * 128 + i * 16 + lk * 4 + r;
        float sm = 0.f;
#pragma unroll
        for (int j = 0; j < 4; ++j) {
          const float v = acc[i][j][r] * ivq[r] * ivk[j];
          sm += v;
          const int col = wcn * 64 + j * 16 + l15;
          sc8[rl * 256 + (((col >> 4) ^ (rl & 15)) << 4) + (col & 15)] = f2f8(v);
        }
        sm = red16(sm);
        if (l15 == 0) atomicAdd(&r1[(long)bz * 1024 + row0 + i * 16 + lk * 4 + r], sm);
      }
    }
    SBAR;
#pragma unroll
    for (int it = 0; it < 8; ++it) {
      const int rl = it * 32 + (tid >> 4);
      const int c = tid & 15;
      us8 v = *(const us8*)&sc8[rl * 256 + ((c ^ (rl & 15)) << 4)];
      *(us8*)&Cb[(long)(bm * 256 + rl) * 1024 + bn * 256 + c * 16] = v;
    }
  } else {
    // final fused fp32 epilogue (R16-verbatim)
    float* scf = (float*)LDSU;
    float* Cb = (float*)O0 + (long)bz * sC;
    const float g = gptr[0];
#pragma unroll
    for (int h = 0; h < 2; ++h) {
      if (wr == h) {
#pragma unroll
        for (int i = 0; i < 8; ++i)
#pragma unroll
          for (int j = 0; j < 4; ++j) {
            const int col = wcn * 64 + j * 16 + l15;
            const int cc = col >> 2, c3 = col & 3;
#pragma unroll
            for (int r = 0; r < 4; ++r) {
              const int rl = i * 16 + lk * 4 + r;
              scf[rl * 256 + ((cc ^ (rl & 15)) << 2) + c3] = acc[i][j][r];
            }
          }
      }
      SBAR;
#pragma unroll
      for (int it = 0; it < 16; ++it) {
        const int rl = it * 8 + wv;
        const int rg = bm * 256 + h * 128 + rl;
        const int c = lane;
        fl4 a4 = *(const fl4*)&scf[rl * 256 + ((c ^ (rl & 15)) << 2)];
        const int cg = bn * 256 + c * 4;
        us4 xv = *(const us4*)&xh[((long)bz * 2048 + rg) * 1024 + cg];
        fl4 tl = *(const fl4*)&tailor[bz * 1024 + cg];
        const float vs = Vsum[bz * 2048 + rg];
        fl4 o;
#pragma unroll
        for (int q = 0; q < 4; ++q) o[q] = b2f(xv[q]) + g * ((vs + a4[q]) * tl[q]);
        *(fl4*)&Cb[(long)rg * 1024 + cg] = o;
      }
      if (h == 0) SBAR;
    }
  }
}

extern "C" void kernel_launch(void* const* d_in, const int* in_sizes, int n_in,
                              void* d_out, int out_size, void* d_ws, size_t ws_size,
                              hipStream_t stream) {
  (void)in_sizes; (void)n_in; (void)out_size;
  const float* x     = (const float*)d_in[0];
  const float* Wq    = (const float*)d_in[1];
  const float* bq    = (const float*)d_in[2];
  const float* Wk    = (const float*)d_in[3];
  const float* bk    = (const float*)d_in[4];
  const float* Wv    = (const float*)d_in[5];
  const float* bv    = (const float*)d_in[6];
  const float* gamma = (const float*)d_in[7];

  // B=16, C=2048, L=D=1024
  const long NE = 16L * 2048 * 1024;

  char* w = (char*)d_ws;
  unsigned char*  QT8 = (unsigned char*)(w);                    // [16][1024][2048] fp8
  unsigned char*  KT8 = (unsigned char*)(w + 33554432L);
  unsigned char*  V8  = (unsigned char*)(w + 67108864L);        // [32768][1024] fp8
  unsigned short* xh  = (unsigned short*)(w + 100663296L);      // bf16 residual (67MB)
  unsigned char*  x8  = (unsigned char*)(w + 167772160L);       // [32768][1024] fp8
  unsigned char*  S8  = (unsigned char*)(w + 201326592L);       // [16][1024][1024] fp8
  size_t off = 218103808L;
  unsigned char* W8   = (unsigned char*)(w + off); off += 3145728;
  char* accbase = w + off;
  float* pq     = (float*)(w + off); off += 65536;
  float* qsum   = (float*)(w + off); off += 65536;
  float* pk     = (float*)(w + off); off += 65536;
  float* Vsum   = (float*)(w + off); off += 131072;
  float* Srow   = (float*)(w + off); off += 65536;
  const size_t accbytes = (size_t)(w + off - accbase);
  float* invq   = (float*)(w + off); off += 65536;
  float* invk   = (float*)(w + off); off += 65536;
  float* tailor = (float*)(w + off); off += 65536;
  float* bqkv   = (float*)(w + off); off += 12288;
  if (ws_size < off) return;

  // 0) zero atomic accumulators
  hipMemsetAsync(accbase, 0, accbytes, stream);

  // 1) casts + bias concat
  k_xcast<<<dim3((unsigned)(NE / 1024)), 256, 0, stream>>>(x, xh, x8, NE);
  k_wcast8<<<dim3(3072), 256, 0, stream>>>(Wq, Wk, Wv, W8);
  k_bias_cat<<<dim3(12), 256, 0, stream>>>(bq, bk, bv, bqkv);

  // 2) merged QKV GEMM (fp8, 16-wave): Q,K transposed fp8; V fp8 + reductions
  k_g16qkv8<<<dim3(12, 128, 1), 1024, 0, stream>>>(
      x8, W8, QT8, KT8, V8, 1024, bqkv, pq, qsum, pk, Vsum);

  // 3) inverse norms
  k_norms_fin<<<dim3(64), 256, 0, stream>>>(pq, pk, invq, invk);

  // 4) S8 = fp8(invq.(QT8 x KT8^T).invk) per batch (fp8, 8-wave; M=N=1024, K=2048)
  k_g8f8<4><<<dim3(4, 4, 16), 512, 0, stream>>>(
      QT8, KT8, S8, 2048, 1024L * 2048, 1024L * 2048, 1024L * 1024,
      Srow, invq, invk, nullptr, nullptr, nullptr, nullptr);

  // 5) tailor
  k_tailor_fin<<<dim3(64), 256, 0, stream>>>(Srow, invq, qsum, tailor);

  // 6) out = xh + gamma*(Vsum + V8 x S8^T) * tailor   (fp8, 8-wave; K=1024)
  k_g8f8<1><<<dim3(4, 8, 16), 512, 0, stream>>>(
      V8, S8, d_out, 1024, 2048L * 1024, 1024L * 1024, 2048L * 1024,
      nullptr, nullptr, nullptr, xh, Vsum, tailor, gamma);
}

// Round 19
// 344.103 us; speedup vs baseline: 2.5437x; 1.0183x over previous
//
#include <hip/hip_runtime.h>
#include <cstdint>

#define DEV static __device__ __forceinline__

typedef __attribute__((ext_vector_type(4))) float f32x4;
typedef __attribute__((ext_vector_type(4))) float fl4;
typedef __attribute__((ext_vector_type(4))) unsigned short us4;
typedef __attribute__((ext_vector_type(8))) unsigned short us8;
typedef __attribute__((ext_vector_type(2))) long l2v;          // 2 x i64 (one b128)

DEV float b2f(unsigned short u) {
  union { unsigned int i; float f; } c; c.i = ((unsigned int)u) << 16; return c.f;
}
DEV unsigned short f2b(float f) {   // RNE float -> bf16 bits
  union { float f; unsigned int i; } c; c.f = f;
  unsigned int u = c.i;
  u += 0x7fffu + ((u >> 16) & 1u);
  return (unsigned short)(u >> 16);
}
DEV unsigned int f4_to_fp8x4(float a, float b, float c, float d) {  // 4 x e4m3 packed
  int r = __builtin_amdgcn_cvt_pk_fp8_f32(a, b, 0, false);
  r = __builtin_amdgcn_cvt_pk_fp8_f32(c, d, r, true);
  return (unsigned int)r;
}
DEV unsigned char f2f8(float v) {   // scalar e4m3
  return (unsigned char)__builtin_amdgcn_cvt_pk_fp8_f32(v, v, 0, false);
}

DEV void gload16(const void* g, void* l) {  // async global->LDS, 16B/lane
  __builtin_amdgcn_global_load_lds(
      (const __attribute__((address_space(1))) unsigned int*)g,
      (__attribute__((address_space(3))) unsigned int*)l, 16, 0, 0);
}

DEV float red16(float v) {  // reduce across 16 lanes sharing lk (xor low 4 bits)
  v += __shfl_xor(v, 1); v += __shfl_xor(v, 2);
  v += __shfl_xor(v, 4); v += __shfl_xor(v, 8);
  return v;
}
DEV float red4lk(float v) { // reduce across the 4 lk groups (xor bits 4,5)
  v += __shfl_xor(v, 16); v += __shfl_xor(v, 32);
  return v;
}

// ---------------- x -> bf16 (residual) + fp8 (GEMM A operand) ----------------
__global__ __launch_bounds__(256) void k_xcast(const float* __restrict__ src,
                                               unsigned short* __restrict__ dh,
                                               unsigned char* __restrict__ d8, long n) {
  long i = ((long)blockIdx.x * 256 + threadIdx.x) * 4;
  if (i >= n) return;
  fl4 v = *(const fl4*)(src + i);
  us4 o;
  o[0] = f2b(v[0]); o[1] = f2b(v[1]); o[2] = f2b(v[2]); o[3] = f2b(v[3]);
  *(us4*)(dh + i) = o;
  *(unsigned int*)(d8 + i) = f4_to_fp8x4(v[0], v[1], v[2], v[3]);
}

// ---------------- Wq|Wk|Wv -> one contiguous fp8 buffer ----------------
__global__ __launch_bounds__(256) void k_wcast8(const float* __restrict__ wq,
                                                const float* __restrict__ wk,
                                                const float* __restrict__ wv,
                                                unsigned char* __restrict__ dst) {
  const long i = ((long)blockIdx.x * 256 + threadIdx.x) * 4;   // [0, 3M)
  const int seg = (int)(i >> 20);
  const float* s = seg == 0 ? wq : (seg == 1 ? wk : wv);
  fl4 v = *(const fl4*)(s + (i & 1048575));
  *(unsigned int*)(dst + i) = f4_to_fp8x4(v[0], v[1], v[2], v[3]);
}

// ---------------- concat biases into 3072-float buffer ----------------
__global__ __launch_bounds__(256) void k_bias_cat(const float* __restrict__ bq,
                                                  const float* __restrict__ bk,
                                                  const float* __restrict__ bv,
                                                  float* __restrict__ o) {
  const int t = blockIdx.x * 256 + threadIdx.x;   // 3072
  o[t] = t < 1024 ? bq[t] : (t < 2048 ? bk[t - 1024] : bv[t - 2048]);
}

#define MFMA_FP8(A, B, C) __builtin_amdgcn_mfma_f32_16x16x32_fp8_fp8((A), (B), (C), 0, 0, 0)
#define SBAR   __builtin_amdgcn_s_barrier()

// ================= 16-WAVE fp8 QKV (R18-verbatim) ======================================
__global__ __launch_bounds__(1024, 4)
void k_g16qkv8(const unsigned char* __restrict__ A,
               const unsigned char* __restrict__ Bt,
               unsigned char* __restrict__ QT8, unsigned char* __restrict__ KT8,
               unsigned char* __restrict__ Vout8,
               int Kb,
               const float* __restrict__ bias,
               float* __restrict__ r1, float* __restrict__ r2,
               float* __restrict__ r3, float* __restrict__ r4) {
  __shared__ __align__(16) unsigned char LDSU[131072];

  const int tid = threadIdx.x;
  const int wv = tid >> 6, lane = tid & 63;
  const int wr = wv >> 2, wcn = wv & 3;          // 4 x 4 wave grid, 64x64 each
  const int l15 = lane & 15, lk = lane >> 4;

  const int nx = gridDim.x;
  const int nwg = nx * gridDim.y;
  const int lin = blockIdx.y * nx + blockIdx.x;
  const int cpx = nwg >> 3;
  const int wg = (lin & 7) * cpx + (lin >> 3);
  const int bn = wg % nx;
  const int bm = wg / nx;

  const unsigned char* Ab = A + (long)bm * 256 * Kb;
  const unsigned char* Bb = Bt + (long)bn * 256 * Kb;

  const int scsw = (tid & 3) ^ ((tid >> 3) & 3);
  const long gOff = (long)(tid >> 2) * Kb + (long)scsw * 16;   // bytes; + t*64
  const int ldsb = wv * 1024;

  const int rdsw = (lk ^ ((l15 >> 1) & 3)) * 16;
  const int abase = (wr * 64 + l15) * 64;
  const int bbase = (wcn * 64 + l15) * 64;

  f32x4 acc[4][4];
#pragma unroll
  for (int i = 0; i < 4; ++i)
#pragma unroll
    for (int j = 0; j < 4; ++j) acc[i][j] = (f32x4){0.f, 0.f, 0.f, 0.f};

#define STAGEQ(T, BUF)                                                        \
  {                                                                           \
    const long kb = (long)(T) * 64;                                           \
    gload16(Ab + kb + gOff, LDSU + (BUF) * 16384 + ldsb);                     \
    gload16(Bb + kb + gOff, LDSU + 65536 + (BUF) * 16384 + ldsb);             \
  }

  STAGEQ(0, 0)
  STAGEQ(1, 1)

  const int NT = Kb >> 6;
  for (int t = 0; t < NT; ++t) {
    if (t < NT - 1) { asm volatile("s_waitcnt vmcnt(2)" ::: "memory"); }
    else            { asm volatile("s_waitcnt vmcnt(0)" ::: "memory"); }
    if ((t & 1) == 0) SBAR;
    if (t + 2 < NT) STAGEQ(t + 2, (t + 2) & 3)

    const unsigned char* Asc = LDSU + (t & 3) * 16384;
    const unsigned char* Bsc = LDSU + 65536 + (t & 3) * 16384;
    l2v Bf[4], Af[4];
#pragma unroll
    for (int j = 0; j < 4; ++j)
      Bf[j] = *(const l2v*)&Bsc[bbase + j * 1024 + rdsw];
#pragma unroll
    for (int i = 0; i < 4; ++i)
      Af[i] = *(const l2v*)&Asc[abase + i * 1024 + rdsw];

    __builtin_amdgcn_s_setprio(1);
#pragma unroll
    for (int i = 0; i < 4; ++i)
#pragma unroll
      for (int j = 0; j < 4; ++j) {
        acc[i][j] = MFMA_FP8(Af[i][0], Bf[j][0], acc[i][j]);
        acc[i][j] = MFMA_FP8(Af[i][1], Bf[j][1], acc[i][j]);
      }
    __builtin_amdgcn_s_setprio(0);
  }
#undef STAGEQ
  SBAR;   // K-loop LDS dead -> scratch

  const int row0 = bm * 256 + wr * 64;
  const int col0 = bn * 256 + wcn * 64;

  const int seg = bn >> 2;             // 0=Q, 1=K, 2=V
  const int b = bm >> 3;               // batch
  float bvj[4];
#pragma unroll
  for (int j = 0; j < 4; ++j) bvj[j] = bias[col0 + j * 16 + l15];
  const int colL0 = col0 & 1023;
  unsigned char* sc8 = LDSU;           // [256][256B] fp8 scratch, 16B cells ^ (row&15)

  if (seg < 2) {
#pragma unroll
    for (int i = 0; i < 4; ++i)
#pragma unroll
      for (int j = 0; j < 4; ++j) {
        const int p = wcn * 64 + j * 16 + l15;
        const int m = wr * 64 + i * 16 + lk * 4;
        const unsigned int pk4 = f4_to_fp8x4(acc[i][j][0] + bvj[j], acc[i][j][1] + bvj[j],
                                             acc[i][j][2] + bvj[j], acc[i][j][3] + bvj[j]);
        *(unsigned int*)&sc8[p * 256 + (((m >> 4) ^ (p & 15)) << 4) + (m & 15)] = pk4;
      }
#pragma unroll
    for (int j = 0; j < 4; ++j) {
      const int colL = colL0 + j * 16 + l15;
      float ss = 0.f, sm = 0.f;
#pragma unroll
      for (int i = 0; i < 4; ++i)
#pragma unroll
        for (int r = 0; r < 4; ++r) {
          const float v = acc[i][j][r] + bvj[j];
          ss += v * v; sm += v;
        }
      ss = red4lk(ss);
      if (seg == 0) sm = red4lk(sm);
      if (lk == 0) {
        atomicAdd(&(seg == 0 ? r1 : r3)[(long)b * 1024 + colL], ss);
        if (seg == 0) atomicAdd(&r2[(long)b * 1024 + colL], sm);
      }
    }
    SBAR;
    unsigned char* tp = (seg == 0 ? QT8 : KT8) + (long)b * 2097152;
    const int P0 = (bn & 3) * 256;
    const int M0 = (bm & 7) * 256;
#pragma unroll
    for (int it = 0; it < 4; ++it) {
      const int p = it * 64 + (tid >> 4);
      const int c = tid & 15;
      us8 v = *(const us8*)&sc8[p * 256 + ((c ^ (p & 15)) << 4)];
      *(us8*)&tp[(long)(P0 + p) * 2048 + M0 + c * 16] = v;
    }
  } else {
#pragma unroll
    for (int i = 0; i < 4; ++i)
#pragma unroll
      for (int r = 0; r < 4; ++r) {
        const int rl = wr * 64 + i * 16 + lk * 4 + r;
        float sm = 0.f;
#pragma unroll
        for (int j = 0; j < 4; ++j) {
          const float v = acc[i][j][r] + bvj[j];
          sm += v;
          const int col = wcn * 64 + j * 16 + l15;
          sc8[rl * 256 + (((col >> 4) ^ (rl & 15)) << 4) + (col & 15)] = f2f8(v);
        }
        sm = red16(sm);
        if (l15 == 0) atomicAdd(&r4[row0 + i * 16 + lk * 4 + r], sm);
      }
    SBAR;
    const int C0 = (bn & 3) * 256;
#pragma unroll
    for (int it = 0; it < 4; ++it) {
      const int rl = it * 64 + (tid >> 4);
      const int c = tid & 15;
      us8 v = *(const us8*)&sc8[rl * 256 + ((c ^ (rl & 15)) << 4)];
      *(us8*)&Vout8[(long)(bm * 256 + rl) * 1024 + C0 + c * 16] = v;
    }
  }
}

// ================= 16-WAVE fp8 S-GEMM (+fused inverse-norm scaling) ====================
// 256x256 NT, BK=64 fp8, 16 waves (4x4 of 64x64). QKV-verbatim K-loop.
// Epilogue: S[p][l] = rsqrt(pq[p])*rsqrt(pk[l])*acc -> fp8 + fp32 scaled row sums.
__global__ __launch_bounds__(1024, 4)
void k_g16s8(const unsigned char* __restrict__ A,
             const unsigned char* __restrict__ Bt,
             unsigned char* __restrict__ Sout,
             int Kb,
             const float* __restrict__ pq, const float* __restrict__ pk,
             float* __restrict__ Srow) {
  __shared__ __align__(16) unsigned char LDSU[131072];

  const int tid = threadIdx.x;
  const int wv = tid >> 6, lane = tid & 63;
  const int wr = wv >> 2, wcn = wv & 3;
  const int l15 = lane & 15, lk = lane >> 4;

  const int nx = gridDim.x;
  const int nwg = nx * gridDim.y;
  const int lin = blockIdx.y * nx + blockIdx.x;
  const int cpx = nwg >> 3;
  const int wg = (lin & 7) * cpx + (lin >> 3);
  const int bn = wg % nx;
  const int bm = wg / nx;
  const int bz = blockIdx.z;

  const unsigned char* Ab = A + (long)bz * 2097152 + (long)bm * 256 * Kb;
  const unsigned char* Bb = Bt + (long)bz * 2097152 + (long)bn * 256 * Kb;

  const int scsw = (tid & 3) ^ ((tid >> 3) & 3);
  const long gOff = (long)(tid >> 2) * Kb + (long)scsw * 16;
  const int ldsb = wv * 1024;

  const int rdsw = (lk ^ ((l15 >> 1) & 3)) * 16;
  const int abase = (wr * 64 + l15) * 64;
  const int bbase = (wcn * 64 + l15) * 64;

  f32x4 acc[4][4];
#pragma unroll
  for (int i = 0; i < 4; ++i)
#pragma unroll
    for (int j = 0; j < 4; ++j) acc[i][j] = (f32x4){0.f, 0.f, 0.f, 0.f};

#define STAGES(T, BUF)                                                        \
  {                                                                           \
    const long kb = (long)(T) * 64;                                           \
    gload16(Ab + kb + gOff, LDSU + (BUF) * 16384 + ldsb);                     \
    gload16(Bb + kb + gOff, LDSU + 65536 + (BUF) * 16384 + ldsb);             \
  }

  STAGES(0, 0)
  STAGES(1, 1)

  const int NT = Kb >> 6;
  for (int t = 0; t < NT; ++t) {
    if (t < NT - 1) { asm volatile("s_waitcnt vmcnt(2)" ::: "memory"); }
    else            { asm volatile("s_waitcnt vmcnt(0)" ::: "memory"); }
    if ((t & 1) == 0) SBAR;
    if (t + 2 < NT) STAGES(t + 2, (t + 2) & 3)

    const unsigned char* Asc = LDSU + (t & 3) * 16384;
    const unsigned char* Bsc = LDSU + 65536 + (t & 3) * 16384;
    l2v Bf[4], Af[4];
#pragma unroll
    for (int j = 0; j < 4; ++j)
      Bf[j] = *(const l2v*)&Bsc[bbase + j * 1024 + rdsw];
#pragma unroll
    for (int i = 0; i < 4; ++i)
      Af[i] = *(const l2v*)&Asc[abase + i * 1024 + rdsw];

    __builtin_amdgcn_s_setprio(1);
#pragma unroll
    for (int i = 0; i < 4; ++i)
#pragma unroll
      for (int j = 0; j < 4; ++j) {
        acc[i][j] = MFMA_FP8(Af[i][0], Bf[j][0], acc[i][j]);
        acc[i][j] = MFMA_FP8(Af[i][1], Bf[j][1], acc[i][j]);
      }
    __builtin_amdgcn_s_setprio(0);
  }
#undef STAGES
  SBAR;

  const int row0 = bm * 256 + wr * 64;
  const int col0 = bn * 256 + wcn * 64;
  unsigned char* sc8 = LDSU;

  float ivk[4];
#pragma unroll
  for (int j = 0; j < 4; ++j) ivk[j] = rsqrtf(pk[bz * 1024 + col0 + j * 16 + l15]);
#pragma unroll
  for (int i = 0; i < 4; ++i)
#pragma unroll
    for (int r = 0; r < 4; ++r) {
      const int rl = wr * 64 + i * 16 + lk * 4 + r;
      const float ivq = rsqrtf(pq[bz * 1024 + row0 + i * 16 + lk * 4 + r]);
      float sm = 0.f;
#pragma unroll
      for (int j = 0; j < 4; ++j) {
        const float v = acc[i][j][r] * ivq * ivk[j];
        sm += v;
        const int col = wcn * 64 + j * 16 + l15;
        sc8[rl * 256 + (((col >> 4) ^ (rl & 15)) << 4) + (col & 15)] = f2f8(v);
      }
      sm = red16(sm);
      if (l15 == 0) atomicAdd(&Srow[(long)bz * 1024 + row0 + i * 16 + lk * 4 + r], sm);
    }
  SBAR;
  unsigned char* Cb = Sout + (long)bz * 1048576;
#pragma unroll
  for (int it = 0; it < 4; ++it) {
    const int rl = it * 64 + (tid >> 4);
    const int c = tid & 15;
    us8 v = *(const us8*)&sc8[rl * 256 + ((c ^ (rl & 15)) << 4)];
    *(us8*)&Cb[(long)(bm * 256 + rl) * 1024 + bn * 256 + c * 16] = v;
  }
}

// ================= 16-WAVE fp8 final GEMM (+fused tailor) ==============================
// out[c][n] = xh + gamma*(Vsum[c] + (V8 x S8^T)[c][n]) * tailor[n], tailor computed
// inline from Srow/pq/qsum. fp32 epilogue staged in 4 quarter-rounds ([64][256] f32).
__global__ __launch_bounds__(1024, 4)
void k_g16fin(const unsigned char* __restrict__ A,
              const unsigned char* __restrict__ Bt,
              float* __restrict__ Out,
              int Kb,
              const unsigned short* __restrict__ xh,
              const float* __restrict__ Vsum,
              const float* __restrict__ Srow,
              const float* __restrict__ pq,
              const float* __restrict__ qsum,
              const float* __restrict__ gptr) {
  __shared__ __align__(16) unsigned char LDSU[131072];

  const int tid = threadIdx.x;
  const int wv = tid >> 6, lane = tid & 63;
  const int wr = wv >> 2, wcn = wv & 3;
  const int l15 = lane & 15, lk = lane >> 4;

  const int nx = gridDim.x;
  const int nwg = nx * gridDim.y;
  const int lin = blockIdx.y * nx + blockIdx.x;
  const int cpx = nwg >> 3;
  const int wg = (lin & 7) * cpx + (lin >> 3);
  const int bn = wg % nx;
  const int bm = wg / nx;
  const int bz = blockIdx.z;

  const unsigned char* Ab = A + (long)bz * 2097152 + (long)bm * 256 * Kb;
  const unsigned char* Bb = Bt + (long)bz * 1048576 + (long)bn * 256 * Kb;

  const int scsw = (tid & 3) ^ ((tid >> 3) & 3);
  const long gOff = (long)(tid >> 2) * Kb + (long)scsw * 16;
  const int ldsb = wv * 1024;

  const int rdsw = (lk ^ ((l15 >> 1) & 3)) * 16;
  const int abase = (wr * 64 + l15) * 64;
  const int bbase = (wcn * 64 + l15) * 64;

  f32x4 acc[4][4];
#pragma unroll
  for (int i = 0; i < 4; ++i)
#pragma unroll
    for (int j = 0; j < 4; ++j) acc[i][j] = (f32x4){0.f, 0.f, 0.f, 0.f};

#define STAGEF(T, BUF)                                                        \
  {                                                                           \
    const long kb = (long)(T) * 64;                                           \
    gload16(Ab + kb + gOff, LDSU + (BUF) * 16384 + ldsb);                     \
    gload16(Bb + kb + gOff, LDSU + 65536 + (BUF) * 16384 + ldsb);             \
  }

  STAGEF(0, 0)
  STAGEF(1, 1)

  const int NT = Kb >> 6;
  for (int t = 0; t < NT; ++t) {
    if (t < NT - 1) { asm volatile("s_waitcnt vmcnt(2)" ::: "memory"); }
    else            { asm volatile("s_waitcnt vmcnt(0)" ::: "memory"); }
    if ((t & 1) == 0) SBAR;
    if (t + 2 < NT) STAGEF(t + 2, (t + 2) & 3)

    const unsigned char* Asc = LDSU + (t & 3) * 16384;
    const unsigned char* Bsc = LDSU + 65536 + (t & 3) * 16384;
    l2v Bf[4], Af[4];
#pragma unroll
    for (int j = 0; j < 4; ++j)
      Bf[j] = *(const l2v*)&Bsc[bbase + j * 1024 + rdsw];
#pragma unroll
    for (int i = 0; i < 4; ++i)
      Af[i] = *(const l2v*)&Asc[abase + i * 1024 + rdsw];

    __builtin_amdgcn_s_setprio(1);
#pragma unroll
    for (int i = 0; i < 4; ++i)
#pragma unroll
      for (int j = 0; j < 4; ++j) {
        acc[i][j] = MFMA_FP8(Af[i][0], Bf[j][0], acc[i][j]);
        acc[i][j] = MFMA_FP8(Af[i][1], Bf[j][1], acc[i][j]);
      }
    __builtin_amdgcn_s_setprio(0);
  }
#undef STAGEF
  SBAR;

  float* scf = (float*)LDSU;           // [64][256] f32 quarter scratch (64 KiB)
  float* Cb = Out + (long)bz * 2097152;
  const float g = gptr[0];
#pragma unroll
  for (int h = 0; h < 4; ++h) {
    if (wr == h) {
#pragma unroll
      for (int i = 0; i < 4; ++i)
#pragma unroll
        for (int j = 0; j < 4; ++j) {
          const int col = wcn * 64 + j * 16 + l15;
          const int cc = col >> 2, c3 = col & 3;
#pragma unroll
          for (int r = 0; r < 4; ++r) {
            const int rl = i * 16 + lk * 4 + r;     // [0,64)
            scf[rl * 256 + ((cc ^ (rl & 15)) << 2) + c3] = acc[i][j][r];
          }
        }
    }
    SBAR;
#pragma unroll
    for (int it = 0; it < 4; ++it) {
      const int rl = it * 16 + wv;                   // [0,64)
      const int rg = bm * 256 + h * 64 + rl;         // [0,2048)
      const int c = lane;                            // f32 cell [0,64)
      fl4 a4 = *(const fl4*)&scf[rl * 256 + ((c ^ (rl & 15)) << 2)];
      const int cg = bn * 256 + c * 4;
      us4 xv = *(const us4*)&xh[((long)bz * 2048 + rg) * 1024 + cg];
      fl4 sr = *(const fl4*)&Srow[bz * 1024 + cg];
      fl4 pq4 = *(const fl4*)&pq[bz * 1024 + cg];
      fl4 qs4 = *(const fl4*)&qsum[bz * 1024 + cg];
      const float vs = Vsum[bz * 2048 + rg];
      fl4 o;
#pragma unroll
      for (int q = 0; q < 4; ++q) {
        const float tl = 1.0f / (1024.0f + sr[q] + 1e-6f * rsqrtf(pq4[q]) * qs4[q]);
        o[q] = b2f(xv[q]) + g * ((vs + a4[q]) * tl);
      }
      *(fl4*)&Cb[(long)rg * 1024 + cg] = o;
    }
    if (h < 3) SBAR;
  }
}

extern "C" void kernel_launch(void* const* d_in, const int* in_sizes, int n_in,
                              void* d_out, int out_size, void* d_ws, size_t ws_size,
                              hipStream_t stream) {
  (void)in_sizes; (void)n_in; (void)out_size;
  const float* x     = (const float*)d_in[0];
  const float* Wq    = (const float*)d_in[1];
  const float* bq    = (const float*)d_in[2];
  const float* Wk    = (const float*)d_in[3];
  const float* bk    = (const float*)d_in[4];
  const float* Wv    = (const float*)d_in[5];
  const float* bv    = (const float*)d_in[6];
  const float* gamma = (const float*)d_in[7];

  // B=16, C=2048, L=D=1024
  const long NE = 16L * 2048 * 1024;

  char* w = (char*)d_ws;
  unsigned char*  QT8 = (unsigned char*)(w);                    // [16][1024][2048] fp8
  unsigned char*  KT8 = (unsigned char*)(w + 33554432L);
  unsigned char*  V8  = (unsigned char*)(w + 67108864L);        // [32768][1024] fp8
  unsigned short* xh  = (unsigned short*)(w + 100663296L);      // bf16 residual (67MB)
  unsigned char*  x8  = (unsigned char*)(w + 167772160L);       // [32768][1024] fp8
  unsigned char*  S8  = (unsigned char*)(w + 201326592L);       // [16][1024][1024] fp8
  size_t off = 218103808L;
  unsigned char* W8   = (unsigned char*)(w + off); off += 3145728;
  char* accbase = w + off;
  float* pq     = (float*)(w + off); off += 65536;
  float* qsum   = (float*)(w + off); off += 65536;
  float* pk     = (float*)(w + off); off += 65536;
  float* Vsum   = (float*)(w + off); off += 131072;
  float* Srow   = (float*)(w + off); off += 65536;
  const size_t accbytes = (size_t)(w + off - accbase);
  float* bqkv   = (float*)(w + off); off += 12288;
  if (ws_size < off) return;

  // 0) zero atomic accumulators
  hipMemsetAsync(accbase, 0, accbytes, stream);

  // 1) casts + bias concat
  k_xcast<<<dim3((unsigned)(NE / 1024)), 256, 0, stream>>>(x, xh, x8, NE);
  k_wcast8<<<dim3(3072), 256, 0, stream>>>(Wq, Wk, Wv, W8);
  k_bias_cat<<<dim3(12), 256, 0, stream>>>(bq, bk, bv, bqkv);

  // 2) merged QKV GEMM (fp8, 16-wave): Q,K transposed fp8; V fp8 + reductions
  k_g16qkv8<<<dim3(12, 128, 1), 1024, 0, stream>>>(
      x8, W8, QT8, KT8, V8, 1024, bqkv, pq, qsum, pk, Vsum);

  // 3) S8 = fp8(rsqrt(pq).(QT8 x KT8^T).rsqrt(pk)) per batch (fused norms; 16-wave)
  k_g16s8<<<dim3(4, 4, 16), 1024, 0, stream>>>(
      QT8, KT8, S8, 2048, pq, pk, Srow);

  // 4) out = xh + gamma*(Vsum + V8 x S8^T) * tailor(Srow,pq,qsum)  (fused tailor; 16-wave)
  k_g16fin<<<dim3(4, 8, 16), 1024, 0, stream>>>(
      V8, S8, (float*)d_out, 1024, xh, Vsum, Srow, pq, qsum, gamma);
}